// Round 6
// baseline (303.230 us; speedup 1.0000x reference)
//
#include <hip/hip_runtime.h>
#include <hip/hip_bf16.h>

// Problem constants: B=4, C=64, H=W=64, HW=4096, P=64, Q=3 (CQ=192)
namespace {
constexpr int IMG    = 262144;   // 64*4096 elems per batch image
constexpr int MS     = 4;        // attention m-split
constexpr int PADIMG = 4356;     // 66*66 padded pixels
constexpr float LOG2E = 1.44269504088896340736f;
// workspace float offsets
constexpr int WBFO  = 0;         // fp16 weights: wbot[9][64][192], wout[9][64][192], wtop[64][192], wcen[64][192]
constexpr int XPADO = 122880;    // fp16 xp/up padded [4][4356][192] = 3345408 halfs (aliased: xp then up)
constexpr int TOPO  = 1795584;   // fp16 topT [b][m][p] = 1048576 halfs
constexpr int CENO  = 2319872;   // fp16 cenT [b][n][p]
constexpr int BOTO  = 2844160;   // fp16 bot  [b][c][m]
constexpr int PVO   = 3368448;   // bf16 PV [4][b][n][c] = 4194304 shorts; aliased as fp32 partials [2][16384][64]
constexpr int MSO   = 5465600;   // m_s [s 4][b 4][group 256]  (group = 16-row n-group)
constexpr int ZSO   = 5469696;   // z_s  (MSO + 4096)
constexpr int MO_   = 5473792;   // M[b]
constexpr int ZO_   = 5473796;   // Z[b]
// total = 5473800 f = 20.9 MB
}

using half8v = __attribute__((ext_vector_type(8))) _Float16;
typedef __attribute__((ext_vector_type(4))) float f32x4;

__device__ __forceinline__ short f2bf(float f) {
    __hip_bfloat16 h = __float2bfloat16(f);
    return *reinterpret_cast<short*>(&h);
}
__device__ __forceinline__ float bf2f(short s) {
    unsigned u = ((unsigned)(unsigned short)s) << 16;
    return __uint_as_float(u);
}

// Weights -> fp16. 3x3: w[o][(p*64+ci)*9+tap] -> wT[tap][o][p*64+ci]; 1x1: [o][192] cast.
// Center weights pre-scaled by log2(e): S' = S*log2e so softmax uses exp2 (saves a mul per element).
__global__ void k_reorder(const float* bw, const float* ow, const float* tw, const float* cw,
                          _Float16* wbf) {
    int idx = blockIdx.x * 256 + threadIdx.x;   // < 245760
    if (idx >= 245760) return;
    if (idx < 221184) {
        int tsel = idx / 110592;
        int r    = idx - tsel * 110592;
        int tap  = r / 12288;
        int rr   = r - tap * 12288;
        int o    = rr / 192;
        int i    = rr - o * 192;
        const float* src = tsel ? ow : bw;
        wbf[idx] = (_Float16)src[o * 1728 + i * 9 + tap];
    } else {
        int j = idx - 221184;
        int tsel = j / 12288;
        int rr   = j - tsel * 12288;
        wbf[idx] = (_Float16)(tsel ? cw[rr] * LOG2E : tw[rr]);
    }
}

// x powers -> padded pixel-major fp16 [b][(h+1)*66+(w+1)][192]. One block per (b, h-row).
__global__ __launch_bounds__(256) void k_pow(const float* __restrict__ x, _Float16* __restrict__ xpad) {
    __shared__ float xs[64 * 65];
    int t = threadIdx.x, bx = blockIdx.x;
    int b = bx >> 6, h = bx & 63;
    #pragma unroll
    for (int it = 0; it < 16; ++it) {
        int idx = it * 256 + t;
        int ci = idx >> 6, wc = idx & 63;
        xs[ci * 65 + wc] = x[b * IMG + ci * 4096 + h * 64 + wc];
    }
    __syncthreads();
    _Float16* dst = xpad + ((size_t)b * PADIMG + (h + 1) * 66 + 1) * 192;
    #pragma unroll
    for (int it = 0; it < 48; ++it) {
        int idx = it * 256 + t;
        int m = idx / 192, k = idx - m * 192;
        int p = k >> 6, ci = k & 63;
        float v = xs[ci * 65 + m];
        float pw = (p == 0) ? v : ((p == 1) ? v * v : v * v * v);
        dst[m * 192 + k] = (_Float16)pw;
    }
}

// 1x1 SelfONN convs as MFMA GEMM from xpad. grid 512 = 256 (b,h) x 2 convs.
__global__ __launch_bounds__(256, 2) void k_conv1m(const _Float16* __restrict__ xpad,
                                                   const _Float16* __restrict__ wtop,
                                                   const _Float16* __restrict__ wcen,
                                                   const float* __restrict__ tb,
                                                   const float* __restrict__ cb,
                                                   _Float16* __restrict__ topd,
                                                   _Float16* __restrict__ cend) {
    int t = threadIdx.x, lane = t & 63, w = t >> 6;
    int l16 = lane & 15, quad = lane >> 4;
    int bx = blockIdx.x;
    int ot = bx >> 8, mt = bx & 255;
    int b = mt >> 6, h = mt & 63;
    const _Float16* wt   = ot ? wcen : wtop;
    const float*    bias = ot ? cb : tb;
    _Float16*       dst  = (ot ? cend : topd) + (size_t)b * IMG;
    const _Float16* abase = xpad + ((size_t)b * PADIMG + (h + 1) * 66 + (w * 16 + l16 + 1)) * 192 + quad * 8;
    const _Float16* bbase = wt + l16 * 192 + quad * 8;
    f32x4 acc[4];
    #pragma unroll
    for (int nf = 0; nf < 4; ++nf) acc[nf] = (f32x4){0.f, 0.f, 0.f, 0.f};
    #pragma unroll
    for (int kc = 0; kc < 6; ++kc) {
        half8v afr = *(const half8v*)&abase[kc * 32];
        #pragma unroll
        for (int nf = 0; nf < 4; ++nf) {
            half8v bfr = *(const half8v*)&bbase[nf * 16 * 192 + kc * 32];
            acc[nf] = __builtin_amdgcn_mfma_f32_16x16x32_f16(afr, bfr, acc[nf], 0, 0, 0);
        }
    }
    _Float16* dp = dst + (size_t)(h * 64 + w * 16) * 64;
    #pragma unroll
    for (int nf = 0; nf < 4; ++nf) {
        float bv = bias[nf * 16 + l16];
        if (ot) bv *= LOG2E;   // center output lives in log2e-scaled domain
        #pragma unroll
        for (int r = 0; r < 4; ++r)
            dp[(quad * 4 + r) * 64 + nf * 16 + l16] = (_Float16)(acc[nf][r] + bv);
    }
}

// 3x3 SelfONN conv as MFMA implicit GEMM, split-K x2, no LDS.
// grid 512 = 2 splits x 256 (b,h). Writes fp32 partials [s][b*4096+m][64].
__global__ __launch_bounds__(256, 2) void k_conv3m(const _Float16* __restrict__ src,
                                                   const _Float16* __restrict__ wt,
                                                   float* __restrict__ part) {
    int t = threadIdx.x, lane = t & 63, w = t >> 6;
    int l16 = lane & 15, quad = lane >> 4;
    int bx = blockIdx.x;
    int s = bx >> 8, mt = bx & 255;
    int b = mt >> 6, h = mt & 63;
    const _Float16* abase = src + ((size_t)b * PADIMG + (h + 1) * 66 + (w * 16 + l16 + 1)) * 192 + quad * 8;
    const _Float16* bbase = wt + l16 * 192 + quad * 8;
    f32x4 acc[4];
    #pragma unroll
    for (int nf = 0; nf < 4; ++nf) acc[nf] = (f32x4){0.f, 0.f, 0.f, 0.f};
    for (int kc = 0; kc < 3; ++kc) {
        int ks = s * 96 + kc * 32;
        #pragma unroll
        for (int tap = 0; tap < 9; ++tap) {
            int dh = tap / 3 - 1, dw = tap % 3 - 1;
            half8v afr = *(const half8v*)&abase[(dh * 66 + dw) * 192 + ks];
            #pragma unroll
            for (int nf = 0; nf < 4; ++nf) {
                half8v bfr = *(const half8v*)&bbase[(tap * 64 + nf * 16) * 192 + ks];
                acc[nf] = __builtin_amdgcn_mfma_f32_16x16x32_f16(afr, bfr, acc[nf], 0, 0, 0);
            }
        }
    }
    float* pp = part + (size_t)s * 1048576 + (size_t)(b * 4096 + h * 64 + w * 16) * 64;
    #pragma unroll
    for (int nf = 0; nf < 4; ++nf)
        #pragma unroll
        for (int r = 0; r < 4; ++r)
            pp[(quad * 4 + r) * 64 + nf * 16 + l16] = acc[nf][r];
}

// Combine split-K partials + bias, transpose [m][o] -> [o][m]. fp16 out (bottom) or fp32 out (final).
__global__ __launch_bounds__(256) void k_combine(const float* __restrict__ part,
                                                 const float* __restrict__ bias,
                                                 _Float16* __restrict__ dh_, float* __restrict__ df) {
    __shared__ float st[64 * 65];
    int t = threadIdx.x, bx = blockIdx.x;
    int b = bx >> 6, h = bx & 63;
    const float* p0 = part + (size_t)(b * 4096 + h * 64) * 64;
    const float* p1 = p0 + 1048576;
    #pragma unroll
    for (int it = 0; it < 16; ++it) {
        int idx = it * 256 + t;
        int m = idx >> 6, o = idx & 63;
        st[m * 65 + o] = p0[idx] + p1[idx];
    }
    __syncthreads();
    #pragma unroll
    for (int it = 0; it < 16; ++it) {
        int idx = it * 256 + t;
        int o = idx >> 6, m = idx & 63;
        float v = st[m * 65 + o] + bias[o];
        size_t oi = (size_t)(b * 64 + o) * 4096 + h * 64 + m;
        if (dh_) dh_[oi] = (_Float16)v; else df[oi] = v;
    }
}

// fp16 MFMA flash attention, global softmax, per-wave online max, BARRIER-FREE.
// All GEMM fragments load directly from global (k-contiguous); only the P
// transpose round-trips through wave-private LDS (XOR-swizzled, conflict-free).
// grid 1024: (strip 64) x (b 4) x (split 4). Wave w owns n-rows st*64+w*16..+15.
__global__ __launch_bounds__(256, 4) void k_attn(float* __restrict__ ws) {
    __shared__ _Float16 lp[64 * 72];     // [n16 0..63][m swizzled]; wave-private rows
    int t    = threadIdx.x;
    int lane = t & 63, w = t >> 6;
    int l16  = lane & 15, quad = lane >> 4;
    int bx = blockIdx.x;
    int st = bx & 63, b = (bx >> 6) & 3, s = bx >> 8;
    int n0 = st * 64;
    const _Float16* topg = (const _Float16*)(ws + TOPO) + (size_t)b * IMG;
    const _Float16* ceng = (const _Float16*)(ws + CENO) + (size_t)b * IMG;
    const _Float16* botg = (const _Float16*)(ws + BOTO) + (size_t)b * IMG;

    // A (center) fragments: fixed per wave
    half8v afr[2];
    #pragma unroll
    for (int kk = 0; kk < 2; ++kk)
        afr[kk] = *(const half8v*)&ceng[(size_t)(n0 + w * 16 + l16) * 64 + kk * 32 + quad * 8];

    // lp addressing (XOR swizzle: col-block = j ^ (n16>>3))
    int q2 = quad >> 1;                       // n16>>3 for writes
    int lpw = (w * 16 + quad * 4) * 72;       // write row base (add r*72)
    int lpr = (w * 16 + l16) * 72;            // read row base
    int rb3 = (l16 >> 3) & 1;                 // n16>>3 for reads

    f32x4 pv[4];
    #pragma unroll
    for (int j = 0; j < 4; ++j) pv[j] = (f32x4){0.f, 0.f, 0.f, 0.f};
    float runm = -3.0e38f, zacc = 0.f;

    for (int tt = 0; tt < 16; ++tt) {
        int m0 = s * 1024 + tt * 64;
        // top B-fragments straight from global (k=p contiguous)
        half8v bfr[2][4];
        #pragma unroll
        for (int kk = 0; kk < 2; ++kk)
            #pragma unroll
            for (int j = 0; j < 4; ++j)
                bfr[kk][j] = *(const half8v*)&topg[(size_t)(m0 + j * 16 + l16) * 64 + kk * 32 + quad * 8];
        // S' = cen' * top (log2e-scaled), 8 MFMAs
        f32x4 sa[4];
        #pragma unroll
        for (int j = 0; j < 4; ++j) sa[j] = (f32x4){0.f, 0.f, 0.f, 0.f};
        #pragma unroll
        for (int kk = 0; kk < 2; ++kk)
            #pragma unroll
            for (int j = 0; j < 4; ++j)
                sa[j] = __builtin_amdgcn_mfma_f32_16x16x32_f16(afr[kk], bfr[kk][j], sa[j], 0, 0, 0);
        // bot B-fragments (k=m contiguous); issued here so L2 latency hides behind softmax
        half8v bb[2][4];
        #pragma unroll
        for (int kk = 0; kk < 2; ++kk)
            #pragma unroll
            for (int j = 0; j < 4; ++j)
                bb[kk][j] = *(const half8v*)&botg[(size_t)(j * 16 + l16) * 4096 + m0 + kk * 32 + quad * 8];
        // wave-local max over this wave's 16x64 tile
        float tm = -3.0e38f;
        #pragma unroll
        for (int j = 0; j < 4; ++j)
            #pragma unroll
            for (int r = 0; r < 4; ++r) tm = fmaxf(tm, sa[j][r]);
        for (int off = 32; off; off >>= 1) tm = fmaxf(tm, __shfl_xor(tm, off, 64));
        float newm = fmaxf(runm, tm);
        if (newm > runm) {          // wave-uniform; skip rescale when max unchanged
            float sc = exp2f(runm - newm);
            zacc *= sc;
            #pragma unroll
            for (int j = 0; j < 4; ++j) pv[j] *= sc;
            runm = newm;
        }
        // exp2 + swizzled P write (wave-private rows; 2 lanes/bank = conflict-free)
        #pragma unroll
        for (int j = 0; j < 4; ++j) {
            int cb = (j ^ q2) * 16 + l16;
            #pragma unroll
            for (int r = 0; r < 4; ++r) {
                float e = exp2f(sa[j][r] - runm);
                zacc += e;
                lp[lpw + r * 72 + cb] = (_Float16)e;
            }
        }
        // P A-fragments back from LDS (b128, swizzle-decoded)
        half8v pa[2];
        #pragma unroll
        for (int kk = 0; kk < 2; ++kk) {
            int jj = kk * 2 + q2;
            pa[kk] = *(half8v*)&lp[lpr + ((jj ^ rb3) * 16) + (quad & 1) * 8];
        }
        // PV += P * bot, 8 MFMAs
        #pragma unroll
        for (int kk = 0; kk < 2; ++kk)
            #pragma unroll
            for (int j = 0; j < 4; ++j)
                pv[j] = __builtin_amdgcn_mfma_f32_16x16x32_f16(pa[kk], bb[kk][j], pv[j], 0, 0, 0);
    }
    for (int off = 32; off; off >>= 1) zacc += __shfl_xor(zacc, off, 64);
    if (lane == 0) {
        ws[MSO + s * 1024 + b * 256 + st * 4 + w] = runm;
        ws[ZSO + s * 1024 + b * 256 + st * 4 + w] = zacc;
    }
    short* pvp = (short*)(ws + PVO) + (size_t)s * 1048576 + (size_t)b * IMG;
    #pragma unroll
    for (int j = 0; j < 4; ++j)
        #pragma unroll
        for (int r = 0; r < 4; ++r)
            pvp[(size_t)(n0 + w * 16 + quad * 4 + r) * 64 + j * 16 + l16] = f2bf(pv[j][r]);
}

// Combine per-(split,16-row-group) (m_s, Z_s) -> global M, Z per batch. 1024 partials per b.
__global__ __launch_bounds__(256) void k_mz(float* __restrict__ ws) {
    int b = blockIdx.x, t = threadIdx.x;
    float mv[4];
    float m = -3.0e38f;
    #pragma unroll
    for (int s = 0; s < 4; ++s) {
        mv[s] = ws[MSO + s * 1024 + b * 256 + t];
        m = fmaxf(m, mv[s]);
    }
    for (int off = 32; off; off >>= 1) m = fmaxf(m, __shfl_xor(m, off, 64));
    __shared__ float rm[4], rz[4];
    if ((t & 63) == 0) rm[t >> 6] = m;
    __syncthreads();
    float M = fmaxf(fmaxf(rm[0], rm[1]), fmaxf(rm[2], rm[3]));
    float z = 0.f;
    #pragma unroll
    for (int s = 0; s < 4; ++s)
        z += ws[ZSO + s * 1024 + b * 256 + t] * exp2f(mv[s] - M);
    for (int off = 32; off; off >>= 1) z += __shfl_xor(z, off, 64);
    if ((t & 63) == 0) rz[t >> 6] = z;
    __syncthreads();
    if (t == 0) { ws[MO_ + b] = M; ws[ZO_ + b] = rz[0] + rz[1] + rz[2] + rz[3]; }
}

// u = x + softmax@bottom (flat add), then u-powers -> padded pixel-major fp16 (aliases xpad).
__global__ __launch_bounds__(256) void k_finalu(const float* __restrict__ x, float* __restrict__ ws,
                                                _Float16* __restrict__ upad) {
    __shared__ float us[64 * 65];
    int t = threadIdx.x, bx = blockIdx.x;
    int b = bx >> 6, h = bx & 63;
    float M = ws[MO_ + b], Z = ws[ZO_ + b];
    const short* pvb = (const short*)(ws + PVO) + (size_t)b * IMG;
    int hg = h >> 4;
    #pragma unroll
    for (int it = 0; it < 16; ++it) {
        int idx = it * 256 + t;
        int ci = idx >> 6, wc = idx & 63;
        int rem = ci * 4096 + h * 64 + wc;
        int grp = ci * 4 + hg;   // n = ci*64+h; 16-row group = n>>4
        float acc = 0.f;
        #pragma unroll
        for (int s = 0; s < MS; ++s) {
            float scl = exp2f(ws[MSO + s * 1024 + b * 256 + grp] - M);
            acc += bf2f(pvb[(size_t)s * 1048576 + rem]) * scl;
        }
        us[ci * 65 + wc] = x[(size_t)b * IMG + rem] + acc / Z;
    }
    __syncthreads();
    _Float16* dst = upad + ((size_t)b * PADIMG + (h + 1) * 66 + 1) * 192;
    #pragma unroll
    for (int it = 0; it < 48; ++it) {
        int idx = it * 256 + t;
        int m = idx / 192, k = idx - m * 192;
        int p = k >> 6, ci = k & 63;
        float v = us[ci * 65 + m];
        float pw = (p == 0) ? v : ((p == 1) ? v * v : v * v * v);
        dst[m * 192 + k] = (_Float16)pw;
    }
}

extern "C" void kernel_launch(void* const* d_in, const int* in_sizes, int n_in,
                              void* d_out, int out_size, void* d_ws, size_t ws_size,
                              hipStream_t stream) {
    (void)in_sizes; (void)n_in; (void)out_size; (void)ws_size;
    const float* x  = (const float*)d_in[0];
    const float* tw = (const float*)d_in[1];
    const float* tb = (const float*)d_in[2];
    const float* cw = (const float*)d_in[3];
    const float* cb = (const float*)d_in[4];
    const float* bw = (const float*)d_in[5];
    const float* bb = (const float*)d_in[6];
    const float* ow = (const float*)d_in[7];
    const float* ob = (const float*)d_in[8];
    float* ws  = (float*)d_ws;
    float* out = (float*)d_out;

    _Float16* wbf  = (_Float16*)(ws + WBFO);
    _Float16* wbot = wbf;
    _Float16* wout = wbf + 110592;
    _Float16* wtop = wbf + 221184;
    _Float16* wcen = wbf + 233472;
    _Float16* xpad = (_Float16*)(ws + XPADO);   // also upad (aliased)
    _Float16* topb = (_Float16*)(ws + TOPO);
    _Float16* cenb = (_Float16*)(ws + CENO);
    _Float16* botb = (_Float16*)(ws + BOTO);
    float*    part = ws + PVO;                  // fp32 partials alias PV region

    hipMemsetAsync(xpad, 0, (size_t)3345408 * sizeof(_Float16), stream);  // zero padded borders
    hipLaunchKernelGGL(k_reorder, dim3(960), dim3(256), 0, stream, bw, ow, tw, cw, wbf);
    hipLaunchKernelGGL(k_pow, dim3(256), dim3(256), 0, stream, x, xpad);
    hipLaunchKernelGGL(k_conv1m, dim3(512), dim3(256), 0, stream, xpad, wtop, wcen, tb, cb, topb, cenb);
    hipLaunchKernelGGL(k_conv3m, dim3(512), dim3(256), 0, stream, xpad, wbot, part);
    hipLaunchKernelGGL(k_combine, dim3(256), dim3(256), 0, stream, part, bb, botb, (float*)nullptr);
    hipLaunchKernelGGL(k_attn, dim3(1024), dim3(256), 0, stream, ws);
    hipLaunchKernelGGL(k_mz, dim3(4), dim3(256), 0, stream, ws);
    hipLaunchKernelGGL(k_finalu, dim3(256), dim3(256), 0, stream, x, ws, xpad);
    hipLaunchKernelGGL(k_conv3m, dim3(512), dim3(256), 0, stream, xpad, wout, part);
    hipLaunchKernelGGL(k_combine, dim3(256), dim3(256), 0, stream, part, ob, (_Float16*)nullptr, out);
}

// Round 7
// 228.976 us; speedup vs baseline: 1.3243x; 1.3243x over previous
//
#include <hip/hip_runtime.h>
#include <hip/hip_bf16.h>

// Problem constants: B=4, C=64, H=W=64, HW=4096, P=64, Q=3 (CQ=192)
namespace {
constexpr int IMG    = 262144;   // 64*4096 elems per batch image
constexpr int MS     = 4;        // attention m-split
constexpr int PADIMG = 4356;     // 66*66 padded pixels
constexpr float LOG2E = 1.44269504088896340736f;
// workspace float offsets
constexpr int WBFO  = 0;         // fp16 weights: wbot[9][64][192], wout[9][64][192], wtop[64][192], wcen[64][192]
constexpr int XPADO = 122880;    // fp16 xp/up padded [4][4356][192] = 3345408 halfs (aliased: xp then up)
constexpr int TOPO  = 1795584;   // fp16 topT [b][m][p] = 1048576 halfs
constexpr int CENO  = 2319872;   // fp16 cenT [b][n][p]
constexpr int BOTO  = 2844160;   // fp16 bot  [b][c][m]
constexpr int PVO   = 3368448;   // bf16 PV [4][b][n][c] = 4194304 shorts; aliased as fp32 partials [2][16384][64]
constexpr int MSO   = 5465600;   // m_s [s 4][b 4][group 256]  (group = 16-row n-group)
constexpr int ZSO   = 5469696;   // z_s  (MSO + 4096)
constexpr int MO_   = 5473792;   // M[b]
constexpr int ZO_   = 5473796;   // Z[b]
// total = 5473800 f = 20.9 MB
}

using half8v = __attribute__((ext_vector_type(8))) _Float16;
typedef __attribute__((ext_vector_type(4))) float f32x4;

__device__ __forceinline__ short f2bf(float f) {
    __hip_bfloat16 h = __float2bfloat16(f);
    return *reinterpret_cast<short*>(&h);
}
__device__ __forceinline__ float bf2f(short s) {
    unsigned u = ((unsigned)(unsigned short)s) << 16;
    return __uint_as_float(u);
}

// Weights -> fp16. 3x3: w[o][(p*64+ci)*9+tap] -> wT[tap][o][p*64+ci]; 1x1: [o][192] cast.
// Center weights pre-scaled by log2(e): S' = S*log2e so softmax uses exp2.
__global__ void k_reorder(const float* bw, const float* ow, const float* tw, const float* cw,
                          _Float16* wbf) {
    int idx = blockIdx.x * 256 + threadIdx.x;   // < 245760
    if (idx >= 245760) return;
    if (idx < 221184) {
        int tsel = idx / 110592;
        int r    = idx - tsel * 110592;
        int tap  = r / 12288;
        int rr   = r - tap * 12288;
        int o    = rr / 192;
        int i    = rr - o * 192;
        const float* src = tsel ? ow : bw;
        wbf[idx] = (_Float16)src[o * 1728 + i * 9 + tap];
    } else {
        int j = idx - 221184;
        int tsel = j / 12288;
        int rr   = j - tsel * 12288;
        wbf[idx] = (_Float16)(tsel ? cw[rr] * LOG2E : tw[rr]);
    }
}

// x powers -> padded pixel-major fp16 [b][(h+1)*66+(w+1)][192]. One block per (b, h-row).
__global__ __launch_bounds__(256) void k_pow(const float* __restrict__ x, _Float16* __restrict__ xpad) {
    __shared__ float xs[64 * 65];
    int t = threadIdx.x, bx = blockIdx.x;
    int b = bx >> 6, h = bx & 63;
    #pragma unroll
    for (int it = 0; it < 16; ++it) {
        int idx = it * 256 + t;
        int ci = idx >> 6, wc = idx & 63;
        xs[ci * 65 + wc] = x[b * IMG + ci * 4096 + h * 64 + wc];
    }
    __syncthreads();
    _Float16* dst = xpad + ((size_t)b * PADIMG + (h + 1) * 66 + 1) * 192;
    #pragma unroll
    for (int it = 0; it < 48; ++it) {
        int idx = it * 256 + t;
        int m = idx / 192, k = idx - m * 192;
        int p = k >> 6, ci = k & 63;
        float v = xs[ci * 65 + m];
        float pw = (p == 0) ? v : ((p == 1) ? v * v : v * v * v);
        dst[m * 192 + k] = (_Float16)pw;
    }
}

// 1x1 SelfONN convs as MFMA GEMM from xpad. grid 512 = 256 (b,h) x 2 convs.
__global__ __launch_bounds__(256, 2) void k_conv1m(const _Float16* __restrict__ xpad,
                                                   const _Float16* __restrict__ wtop,
                                                   const _Float16* __restrict__ wcen,
                                                   const float* __restrict__ tb,
                                                   const float* __restrict__ cb,
                                                   _Float16* __restrict__ topd,
                                                   _Float16* __restrict__ cend) {
    int t = threadIdx.x, lane = t & 63, w = t >> 6;
    int l16 = lane & 15, quad = lane >> 4;
    int bx = blockIdx.x;
    int ot = bx >> 8, mt = bx & 255;
    int b = mt >> 6, h = mt & 63;
    const _Float16* wt   = ot ? wcen : wtop;
    const float*    bias = ot ? cb : tb;
    _Float16*       dst  = (ot ? cend : topd) + (size_t)b * IMG;
    const _Float16* abase = xpad + ((size_t)b * PADIMG + (h + 1) * 66 + (w * 16 + l16 + 1)) * 192 + quad * 8;
    const _Float16* bbase = wt + l16 * 192 + quad * 8;
    f32x4 acc[4];
    #pragma unroll
    for (int nf = 0; nf < 4; ++nf) acc[nf] = (f32x4){0.f, 0.f, 0.f, 0.f};
    #pragma unroll
    for (int kc = 0; kc < 6; ++kc) {
        half8v afr = *(const half8v*)&abase[kc * 32];
        #pragma unroll
        for (int nf = 0; nf < 4; ++nf) {
            half8v bfr = *(const half8v*)&bbase[nf * 16 * 192 + kc * 32];
            acc[nf] = __builtin_amdgcn_mfma_f32_16x16x32_f16(afr, bfr, acc[nf], 0, 0, 0);
        }
    }
    _Float16* dp = dst + (size_t)(h * 64 + w * 16) * 64;
    #pragma unroll
    for (int nf = 0; nf < 4; ++nf) {
        float bv = bias[nf * 16 + l16];
        if (ot) bv *= LOG2E;   // center output lives in log2e-scaled domain
        #pragma unroll
        for (int r = 0; r < 4; ++r)
            dp[(quad * 4 + r) * 64 + nf * 16 + l16] = (_Float16)(acc[nf][r] + bv);
    }
}

// 3x3 SelfONN conv as MFMA implicit GEMM, split-K x2, no LDS.
// grid 512 = 2 splits x 256 (b,h). Writes fp32 partials [s][b*4096+m][64].
__global__ __launch_bounds__(256, 2) void k_conv3m(const _Float16* __restrict__ src,
                                                   const _Float16* __restrict__ wt,
                                                   float* __restrict__ part) {
    int t = threadIdx.x, lane = t & 63, w = t >> 6;
    int l16 = lane & 15, quad = lane >> 4;
    int bx = blockIdx.x;
    int s = bx >> 8, mt = bx & 255;
    int b = mt >> 6, h = mt & 63;
    const _Float16* abase = src + ((size_t)b * PADIMG + (h + 1) * 66 + (w * 16 + l16 + 1)) * 192 + quad * 8;
    const _Float16* bbase = wt + l16 * 192 + quad * 8;
    f32x4 acc[4];
    #pragma unroll
    for (int nf = 0; nf < 4; ++nf) acc[nf] = (f32x4){0.f, 0.f, 0.f, 0.f};
    for (int kc = 0; kc < 3; ++kc) {
        int ks = s * 96 + kc * 32;
        #pragma unroll
        for (int tap = 0; tap < 9; ++tap) {
            int dh = tap / 3 - 1, dw = tap % 3 - 1;
            half8v afr = *(const half8v*)&abase[(dh * 66 + dw) * 192 + ks];
            #pragma unroll
            for (int nf = 0; nf < 4; ++nf) {
                half8v bfr = *(const half8v*)&bbase[(tap * 64 + nf * 16) * 192 + ks];
                acc[nf] = __builtin_amdgcn_mfma_f32_16x16x32_f16(afr, bfr, acc[nf], 0, 0, 0);
            }
        }
    }
    float* pp = part + (size_t)s * 1048576 + (size_t)(b * 4096 + h * 64 + w * 16) * 64;
    #pragma unroll
    for (int nf = 0; nf < 4; ++nf)
        #pragma unroll
        for (int r = 0; r < 4; ++r)
            pp[(quad * 4 + r) * 64 + nf * 16 + l16] = acc[nf][r];
}

// Combine split-K partials + bias, transpose [m][o] -> [o][m]. fp16 out (bottom) or fp32 out (final).
__global__ __launch_bounds__(256) void k_combine(const float* __restrict__ part,
                                                 const float* __restrict__ bias,
                                                 _Float16* __restrict__ dh_, float* __restrict__ df) {
    __shared__ float st[64 * 65];
    int t = threadIdx.x, bx = blockIdx.x;
    int b = bx >> 6, h = bx & 63;
    const float* p0 = part + (size_t)(b * 4096 + h * 64) * 64;
    const float* p1 = p0 + 1048576;
    #pragma unroll
    for (int it = 0; it < 16; ++it) {
        int idx = it * 256 + t;
        int m = idx >> 6, o = idx & 63;
        st[m * 65 + o] = p0[idx] + p1[idx];
    }
    __syncthreads();
    #pragma unroll
    for (int it = 0; it < 16; ++it) {
        int idx = it * 256 + t;
        int o = idx >> 6, m = idx & 63;
        float v = st[m * 65 + o] + bias[o];
        size_t oi = (size_t)(b * 64 + o) * 4096 + h * 64 + m;
        if (dh_) dh_[oi] = (_Float16)v; else df[oi] = v;
    }
}

// fp16 MFMA flash attention, global softmax, per-wave online max.
// LDS staging (cross-wave reuse) + REGISTER PREFETCH pipeline: tile tt+1's
// global loads issue right after tile tt's barrier, landing a full compute
// tile later — barriers no longer drain vmem. lp is wave-private rows +
// XOR swizzle, read without a barrier (same-wave lgkmcnt ordering).
// grid 1024: (strip 64) x (b 4) x (split 4).
__global__ __launch_bounds__(256, 4) void k_attn(float* __restrict__ ws) {
    __shared__ _Float16 ltop[64 * 72];   // [m][p]
    __shared__ _Float16 lbot[64 * 72];   // [c][m]
    __shared__ _Float16 lp[64 * 72];     // [n][m swizzled]; wave-private rows
    int t    = threadIdx.x;
    int lane = t & 63, w = t >> 6;
    int l16  = lane & 15, quad = lane >> 4;
    int bx = blockIdx.x;
    int st = bx & 63, b = (bx >> 6) & 3, s = bx >> 8;
    int n0 = st * 64;
    const _Float16* topg = (const _Float16*)(ws + TOPO) + (size_t)b * IMG;
    const _Float16* ceng = (const _Float16*)(ws + CENO) + (size_t)b * IMG;
    const _Float16* botg = (const _Float16*)(ws + BOTO) + (size_t)b * IMG;

    // A (center) fragments: fixed per wave
    half8v afr[2];
    #pragma unroll
    for (int kk = 0; kk < 2; ++kk)
        afr[kk] = *(const half8v*)&ceng[(size_t)(n0 + w * 16 + l16) * 64 + kk * 32 + quad * 8];

    // staging addressing: thread t covers rows r0=t>>3 and r1=r0+32, 8 halfs at off
    int r0 = t >> 3, r1 = r0 + 32, off = (t & 7) * 8;

    // lp swizzle addressing (col-block = j ^ (within-wave-row>>3))
    int q2 = quad >> 1;
    int lpw = (w * 16 + quad * 4) * 72;
    int lpr = (w * 16 + l16) * 72;
    int rb3 = (l16 >> 3) & 1;

    f32x4 pv[4];
    #pragma unroll
    for (int j = 0; j < 4; ++j) pv[j] = (f32x4){0.f, 0.f, 0.f, 0.f};
    float runm = -3.0e38f, zacc = 0.f;

    // prologue: prefetch tile 0
    int mp = s * 1024;
    half8v rt0 = *(const half8v*)&topg[(size_t)(mp + r0) * 64 + off];
    half8v rt1 = *(const half8v*)&topg[(size_t)(mp + r1) * 64 + off];
    half8v rb0 = *(const half8v*)&botg[(size_t)r0 * 4096 + mp + off];
    half8v rb1 = *(const half8v*)&botg[(size_t)r1 * 4096 + mp + off];

    for (int tt = 0; tt < 16; ++tt) {
        __syncthreads();   // prev-tile LDS reads done
        *(half8v*)&ltop[r0 * 72 + off] = rt0;
        *(half8v*)&ltop[r1 * 72 + off] = rt1;
        *(half8v*)&lbot[r0 * 72 + off] = rb0;
        *(half8v*)&lbot[r1 * 72 + off] = rb1;
        __syncthreads();   // tile ready
        if (tt < 15) {     // prefetch next tile; completes during compute below
            int m1 = s * 1024 + (tt + 1) * 64;
            rt0 = *(const half8v*)&topg[(size_t)(m1 + r0) * 64 + off];
            rt1 = *(const half8v*)&topg[(size_t)(m1 + r1) * 64 + off];
            rb0 = *(const half8v*)&botg[(size_t)r0 * 4096 + m1 + off];
            rb1 = *(const half8v*)&botg[(size_t)r1 * 4096 + m1 + off];
        }
        // S' = cen' * top (log2e-scaled), 8 MFMAs/wave
        f32x4 sa[4];
        #pragma unroll
        for (int j = 0; j < 4; ++j) sa[j] = (f32x4){0.f, 0.f, 0.f, 0.f};
        #pragma unroll
        for (int kk = 0; kk < 2; ++kk)
            #pragma unroll
            for (int j = 0; j < 4; ++j) {
                half8v bfr = *(half8v*)&ltop[(j * 16 + l16) * 72 + kk * 32 + quad * 8];
                sa[j] = __builtin_amdgcn_mfma_f32_16x16x32_f16(afr[kk], bfr, sa[j], 0, 0, 0);
            }
        // wave-local max over this wave's 16x64 tile
        float tm = -3.0e38f;
        #pragma unroll
        for (int j = 0; j < 4; ++j)
            #pragma unroll
            for (int r = 0; r < 4; ++r) tm = fmaxf(tm, sa[j][r]);
        for (int o2 = 32; o2; o2 >>= 1) tm = fmaxf(tm, __shfl_xor(tm, o2, 64));
        float newm = fmaxf(runm, tm);
        if (newm > runm) {          // wave-uniform; skip rescale when max unchanged
            float sc = exp2f(runm - newm);
            zacc *= sc;
            #pragma unroll
            for (int j = 0; j < 4; ++j) pv[j] *= sc;
            runm = newm;
        }
        // exp2 + swizzled P write (wave-private rows)
        #pragma unroll
        for (int j = 0; j < 4; ++j) {
            int cb = (j ^ q2) * 16 + l16;
            #pragma unroll
            for (int r = 0; r < 4; ++r) {
                float e = exp2f(sa[j][r] - runm);
                zacc += e;
                lp[lpw + r * 72 + cb] = (_Float16)e;
            }
        }
        // P A-fragments back from LDS (same-wave RAW -> lgkmcnt, no barrier)
        half8v pa[2];
        #pragma unroll
        for (int kk = 0; kk < 2; ++kk) {
            int jj = kk * 2 + q2;
            pa[kk] = *(half8v*)&lp[lpr + ((jj ^ rb3) * 16) + (quad & 1) * 8];
        }
        // PV += P * bot, 8 MFMAs/wave
        #pragma unroll
        for (int kk = 0; kk < 2; ++kk)
            #pragma unroll
            for (int j = 0; j < 4; ++j) {
                half8v bb = *(half8v*)&lbot[(j * 16 + l16) * 72 + kk * 32 + quad * 8];
                pv[j] = __builtin_amdgcn_mfma_f32_16x16x32_f16(pa[kk], bb, pv[j], 0, 0, 0);
            }
    }
    for (int o2 = 32; o2; o2 >>= 1) zacc += __shfl_xor(zacc, o2, 64);
    if (lane == 0) {
        ws[MSO + s * 1024 + b * 256 + st * 4 + w] = runm;
        ws[ZSO + s * 1024 + b * 256 + st * 4 + w] = zacc;
    }
    short* pvp = (short*)(ws + PVO) + (size_t)s * 1048576 + (size_t)b * IMG;
    #pragma unroll
    for (int j = 0; j < 4; ++j)
        #pragma unroll
        for (int r = 0; r < 4; ++r)
            pvp[(size_t)(n0 + w * 16 + quad * 4 + r) * 64 + j * 16 + l16] = f2bf(pv[j][r]);
}

// Combine per-(split,16-row-group) (m_s, Z_s) -> global M, Z per batch. 1024 partials per b.
__global__ __launch_bounds__(256) void k_mz(float* __restrict__ ws) {
    int b = blockIdx.x, t = threadIdx.x;
    float mv[4];
    float m = -3.0e38f;
    #pragma unroll
    for (int s = 0; s < 4; ++s) {
        mv[s] = ws[MSO + s * 1024 + b * 256 + t];
        m = fmaxf(m, mv[s]);
    }
    for (int off = 32; off; off >>= 1) m = fmaxf(m, __shfl_xor(m, off, 64));
    __shared__ float rm[4], rz[4];
    if ((t & 63) == 0) rm[t >> 6] = m;
    __syncthreads();
    float M = fmaxf(fmaxf(rm[0], rm[1]), fmaxf(rm[2], rm[3]));
    float z = 0.f;
    #pragma unroll
    for (int s = 0; s < 4; ++s)
        z += ws[ZSO + s * 1024 + b * 256 + t] * exp2f(mv[s] - M);
    for (int off = 32; off; off >>= 1) z += __shfl_xor(z, off, 64);
    if ((t & 63) == 0) rz[t >> 6] = z;
    __syncthreads();
    if (t == 0) { ws[MO_ + b] = M; ws[ZO_ + b] = rz[0] + rz[1] + rz[2] + rz[3]; }
}

// u = x + softmax@bottom (flat add), then u-powers -> padded pixel-major fp16 (aliases xpad).
__global__ __launch_bounds__(256) void k_finalu(const float* __restrict__ x, float* __restrict__ ws,
                                                _Float16* __restrict__ upad) {
    __shared__ float us[64 * 65];
    int t = threadIdx.x, bx = blockIdx.x;
    int b = bx >> 6, h = bx & 63;
    float M = ws[MO_ + b], Z = ws[ZO_ + b];
    const short* pvb = (const short*)(ws + PVO) + (size_t)b * IMG;
    int hg = h >> 4;
    #pragma unroll
    for (int it = 0; it < 16; ++it) {
        int idx = it * 256 + t;
        int ci = idx >> 6, wc = idx & 63;
        int rem = ci * 4096 + h * 64 + wc;
        int grp = ci * 4 + hg;   // n = ci*64+h; 16-row group = n>>4
        float acc = 0.f;
        #pragma unroll
        for (int s = 0; s < MS; ++s) {
            float scl = exp2f(ws[MSO + s * 1024 + b * 256 + grp] - M);
            acc += bf2f(pvb[(size_t)s * 1048576 + rem]) * scl;
        }
        us[ci * 65 + wc] = x[(size_t)b * IMG + rem] + acc / Z;
    }
    __syncthreads();
    _Float16* dst = upad + ((size_t)b * PADIMG + (h + 1) * 66 + 1) * 192;
    #pragma unroll
    for (int it = 0; it < 48; ++it) {
        int idx = it * 256 + t;
        int m = idx / 192, k = idx - m * 192;
        int p = k >> 6, ci = k & 63;
        float v = us[ci * 65 + m];
        float pw = (p == 0) ? v : ((p == 1) ? v * v : v * v * v);
        dst[m * 192 + k] = (_Float16)pw;
    }
}

extern "C" void kernel_launch(void* const* d_in, const int* in_sizes, int n_in,
                              void* d_out, int out_size, void* d_ws, size_t ws_size,
                              hipStream_t stream) {
    (void)in_sizes; (void)n_in; (void)out_size; (void)ws_size;
    const float* x  = (const float*)d_in[0];
    const float* tw = (const float*)d_in[1];
    const float* tb = (const float*)d_in[2];
    const float* cw = (const float*)d_in[3];
    const float* cb = (const float*)d_in[4];
    const float* bw = (const float*)d_in[5];
    const float* bb = (const float*)d_in[6];
    const float* ow = (const float*)d_in[7];
    const float* ob = (const float*)d_in[8];
    float* ws  = (float*)d_ws;
    float* out = (float*)d_out;

    _Float16* wbf  = (_Float16*)(ws + WBFO);
    _Float16* wbot = wbf;
    _Float16* wout = wbf + 110592;
    _Float16* wtop = wbf + 221184;
    _Float16* wcen = wbf + 233472;
    _Float16* xpad = (_Float16*)(ws + XPADO);   // also upad (aliased)
    _Float16* topb = (_Float16*)(ws + TOPO);
    _Float16* cenb = (_Float16*)(ws + CENO);
    _Float16* botb = (_Float16*)(ws + BOTO);
    float*    part = ws + PVO;                  // fp32 partials alias PV region

    hipMemsetAsync(xpad, 0, (size_t)3345408 * sizeof(_Float16), stream);  // zero padded borders
    hipLaunchKernelGGL(k_reorder, dim3(960), dim3(256), 0, stream, bw, ow, tw, cw, wbf);
    hipLaunchKernelGGL(k_pow, dim3(256), dim3(256), 0, stream, x, xpad);
    hipLaunchKernelGGL(k_conv1m, dim3(512), dim3(256), 0, stream, xpad, wtop, wcen, tb, cb, topb, cenb);
    hipLaunchKernelGGL(k_conv3m, dim3(512), dim3(256), 0, stream, xpad, wbot, part);
    hipLaunchKernelGGL(k_combine, dim3(256), dim3(256), 0, stream, part, bb, botb, (float*)nullptr);
    hipLaunchKernelGGL(k_attn, dim3(1024), dim3(256), 0, stream, ws);
    hipLaunchKernelGGL(k_mz, dim3(4), dim3(256), 0, stream, ws);
    hipLaunchKernelGGL(k_finalu, dim3(256), dim3(256), 0, stream, x, ws, xpad);
    hipLaunchKernelGGL(k_conv3m, dim3(512), dim3(256), 0, stream, xpad, wout, part);
    hipLaunchKernelGGL(k_combine, dim3(256), dim3(256), 0, stream, part, ob, (_Float16*)nullptr, out);
}

// Round 8
// 224.561 us; speedup vs baseline: 1.3503x; 1.0197x over previous
//
#include <hip/hip_runtime.h>
#include <hip/hip_bf16.h>

// Problem constants: B=4, C=64, H=W=64, HW=4096, P=64, Q=3 (CQ=192)
namespace {
constexpr int IMG    = 262144;   // 64*4096 elems per batch image
constexpr int MS     = 4;        // attention m-split
constexpr int PADIMG = 4356;     // 66*66 padded pixels
constexpr float LOG2E = 1.44269504088896340736f;
// workspace float offsets
constexpr int WBFO  = 0;         // fp16 weights: wbot[9][64][192], wout[9][64][192], wtop[64][192], wcen[64][192]
constexpr int XPADO = 122880;    // fp16 xp/up padded [4][4356][192] = 3345408 halfs (aliased: xp then up)
constexpr int TOPO  = 1795584;   // fp16 topT [b][m][p] = 1048576 halfs
constexpr int CENO  = 2319872;   // fp16 cenT [b][n][p]
constexpr int BOTO  = 2844160;   // fp16 bot  [b][c][m]
constexpr int PVO   = 3368448;   // bf16 PV [4][b][n][c] = 4194304 shorts; aliased as fp16 conv partials [4][b][ch][m]
constexpr int MSO   = 5465600;   // m_s [s 4][b 4][group 256]  (group = 16-row n-group)
constexpr int ZSO   = 5469696;   // z_s  (MSO + 4096)
constexpr int MO_   = 5473792;   // M[b]
constexpr int ZO_   = 5473796;   // Z[b]
// total = 5473800 f = 20.9 MB
}

using half8v = __attribute__((ext_vector_type(8))) _Float16;
using half4v = __attribute__((ext_vector_type(4))) _Float16;
typedef __attribute__((ext_vector_type(4))) float f32x4;

__device__ __forceinline__ short f2bf(float f) {
    __hip_bfloat16 h = __float2bfloat16(f);
    return *reinterpret_cast<short*>(&h);
}
__device__ __forceinline__ float bf2f(short s) {
    unsigned u = ((unsigned)(unsigned short)s) << 16;
    return __uint_as_float(u);
}

// Weights -> fp16. 3x3: w[o][(p*64+ci)*9+tap] -> wT[tap][o][p*64+ci]; 1x1: [o][192] cast.
// Center weights pre-scaled by log2(e): S' = S*log2e so softmax uses exp2.
__global__ void k_reorder(const float* bw, const float* ow, const float* tw, const float* cw,
                          _Float16* wbf) {
    int idx = blockIdx.x * 256 + threadIdx.x;   // < 245760
    if (idx >= 245760) return;
    if (idx < 221184) {
        int tsel = idx / 110592;
        int r    = idx - tsel * 110592;
        int tap  = r / 12288;
        int rr   = r - tap * 12288;
        int o    = rr / 192;
        int i    = rr - o * 192;
        const float* src = tsel ? ow : bw;
        wbf[idx] = (_Float16)src[o * 1728 + i * 9 + tap];
    } else {
        int j = idx - 221184;
        int tsel = j / 12288;
        int rr   = j - tsel * 12288;
        wbf[idx] = (_Float16)(tsel ? cw[rr] * LOG2E : tw[rr]);
    }
}

// x powers -> padded pixel-major fp16 [b][(h+1)*66+(w+1)][192]. One block per (b, h-row).
__global__ __launch_bounds__(256) void k_pow(const float* __restrict__ x, _Float16* __restrict__ xpad) {
    __shared__ float xs[64 * 65];
    int t = threadIdx.x, bx = blockIdx.x;
    int b = bx >> 6, h = bx & 63;
    #pragma unroll
    for (int it = 0; it < 16; ++it) {
        int idx = it * 256 + t;
        int ci = idx >> 6, wc = idx & 63;
        xs[ci * 65 + wc] = x[b * IMG + ci * 4096 + h * 64 + wc];
    }
    __syncthreads();
    _Float16* dst = xpad + ((size_t)b * PADIMG + (h + 1) * 66 + 1) * 192;
    #pragma unroll
    for (int it = 0; it < 48; ++it) {
        int idx = it * 256 + t;
        int m = idx / 192, k = idx - m * 192;
        int p = k >> 6, ci = k & 63;
        float v = xs[ci * 65 + m];
        float pw = (p == 0) ? v : ((p == 1) ? v * v : v * v * v);
        dst[m * 192 + k] = (_Float16)pw;
    }
}

// 1x1 SelfONN convs as MFMA GEMM from xpad. grid 512 = 256 (b,h) x 2 convs.
__global__ __launch_bounds__(256, 2) void k_conv1m(const _Float16* __restrict__ xpad,
                                                   const _Float16* __restrict__ wtop,
                                                   const _Float16* __restrict__ wcen,
                                                   const float* __restrict__ tb,
                                                   const float* __restrict__ cb,
                                                   _Float16* __restrict__ topd,
                                                   _Float16* __restrict__ cend) {
    int t = threadIdx.x, lane = t & 63, w = t >> 6;
    int l16 = lane & 15, quad = lane >> 4;
    int bx = blockIdx.x;
    int ot = bx >> 8, mt = bx & 255;
    int b = mt >> 6, h = mt & 63;
    const _Float16* wt   = ot ? wcen : wtop;
    const float*    bias = ot ? cb : tb;
    _Float16*       dst  = (ot ? cend : topd) + (size_t)b * IMG;
    const _Float16* abase = xpad + ((size_t)b * PADIMG + (h + 1) * 66 + (w * 16 + l16 + 1)) * 192 + quad * 8;
    const _Float16* bbase = wt + l16 * 192 + quad * 8;
    f32x4 acc[4];
    #pragma unroll
    for (int nf = 0; nf < 4; ++nf) acc[nf] = (f32x4){0.f, 0.f, 0.f, 0.f};
    #pragma unroll
    for (int kc = 0; kc < 6; ++kc) {
        half8v afr = *(const half8v*)&abase[kc * 32];
        #pragma unroll
        for (int nf = 0; nf < 4; ++nf) {
            half8v bfr = *(const half8v*)&bbase[nf * 16 * 192 + kc * 32];
            acc[nf] = __builtin_amdgcn_mfma_f32_16x16x32_f16(afr, bfr, acc[nf], 0, 0, 0);
        }
    }
    _Float16* dp = dst + (size_t)(h * 64 + w * 16) * 64;
    #pragma unroll
    for (int nf = 0; nf < 4; ++nf) {
        float bv = bias[nf * 16 + l16];
        if (ot) bv *= LOG2E;   // center output lives in log2e-scaled domain
        #pragma unroll
        for (int r = 0; r < 4; ++r)
            dp[(quad * 4 + r) * 64 + nf * 16 + l16] = (_Float16)(acc[nf][r] + bv);
    }
}

// 3x3 SelfONN conv as MFMA implicit GEMM, split-K x4, no LDS.
// grid 1024 = 4 splits x 256 (b,h) -> 4 blocks/CU. K = 54 (tap,c6) chunks
// partitioned 14/14/13/13. Partials fp16 CHANNEL-MAJOR [s][b][ch][m]
// (px-contiguous half4 packed stores; combine needs no transpose).
__global__ __launch_bounds__(256, 2) void k_conv3m(const _Float16* __restrict__ src,
                                                   const _Float16* __restrict__ wt,
                                                   _Float16* __restrict__ part) {
    int t = threadIdx.x, lane = t & 63, w = t >> 6;
    int l16 = lane & 15, quad = lane >> 4;
    int bx = blockIdx.x;
    int s = bx >> 8, mt = bx & 255;
    int b = mt >> 6, h = mt & 63;
    const _Float16* abase = src + ((size_t)b * PADIMG + (h + 1) * 66 + (w * 16 + l16 + 1)) * 192 + quad * 8;
    const _Float16* bbase = wt + l16 * 192 + quad * 8;
    int lo = (s < 2) ? s * 14 : 28 + (s - 2) * 13;
    int hi = lo + ((s < 2) ? 14 : 13);
    f32x4 acc[4];
    #pragma unroll
    for (int nf = 0; nf < 4; ++nf) acc[nf] = (f32x4){0.f, 0.f, 0.f, 0.f};
    for (int p = lo; p < hi; ++p) {
        int tap = p / 6, c6 = p - tap * 6;
        int dh = tap / 3 - 1, dw = tap % 3 - 1;
        half8v afr = *(const half8v*)&abase[(dh * 66 + dw) * 192 + c6 * 32];
        #pragma unroll
        for (int nf = 0; nf < 4; ++nf) {
            half8v bfr = *(const half8v*)&bbase[(tap * 64 + nf * 16) * 192 + c6 * 32];
            acc[nf] = __builtin_amdgcn_mfma_f32_16x16x32_f16(afr, bfr, acc[nf], 0, 0, 0);
        }
    }
    _Float16* pp = part + (size_t)s * 1048576 + (size_t)b * 262144 + h * 64 + w * 16 + quad * 4;
    #pragma unroll
    for (int nf = 0; nf < 4; ++nf) {
        half4v o;
        #pragma unroll
        for (int r = 0; r < 4; ++r) o[r] = (_Float16)acc[nf][r];
        *(half4v*)&pp[(size_t)(nf * 16 + l16) * 4096] = o;
    }
}

// Sum 4 fp16 split-K partials + bias. Pure elementwise (layouts already match).
// grid 512 x 256, 8 elems/thread. fp16 out (bottom) or fp32 out (final).
__global__ __launch_bounds__(256) void k_combine(const _Float16* __restrict__ part,
                                                 const float* __restrict__ bias,
                                                 _Float16* __restrict__ dh_, float* __restrict__ df) {
    int e = (blockIdx.x * 256 + threadIdx.x) * 8;   // flat [b][ch][m] element base
    int off = e & 262143;
    int ch = off >> 12;
    float bv = bias[ch];
    float acc[8] = {};
    #pragma unroll
    for (int s = 0; s < 4; ++s) {
        half8v p = *(const half8v*)&part[(size_t)s * 1048576 + e];
        #pragma unroll
        for (int i = 0; i < 8; ++i) acc[i] += (float)p[i];
    }
    if (dh_) {
        half8v o;
        #pragma unroll
        for (int i = 0; i < 8; ++i) o[i] = (_Float16)(acc[i] + bv);
        *(half8v*)&dh_[e] = o;
    } else {
        float4 o0 = make_float4(acc[0] + bv, acc[1] + bv, acc[2] + bv, acc[3] + bv);
        float4 o1 = make_float4(acc[4] + bv, acc[5] + bv, acc[6] + bv, acc[7] + bv);
        *(float4*)&df[e]     = o0;
        *(float4*)&df[e + 4] = o1;
    }
}

// fp16 MFMA flash attention, global softmax, per-wave online max.
// LDS staging (cross-wave reuse) + register prefetch pipeline. lp is
// wave-private rows + XOR swizzle, read without a barrier.
// grid 1024: (strip 64) x (b 4) x (split 4).
__global__ __launch_bounds__(256, 4) void k_attn(float* __restrict__ ws) {
    __shared__ _Float16 ltop[64 * 72];   // [m][p]
    __shared__ _Float16 lbot[64 * 72];   // [c][m]
    __shared__ _Float16 lp[64 * 72];     // [n][m swizzled]; wave-private rows
    int t    = threadIdx.x;
    int lane = t & 63, w = t >> 6;
    int l16  = lane & 15, quad = lane >> 4;
    int bx = blockIdx.x;
    int st = bx & 63, b = (bx >> 6) & 3, s = bx >> 8;
    int n0 = st * 64;
    const _Float16* topg = (const _Float16*)(ws + TOPO) + (size_t)b * IMG;
    const _Float16* ceng = (const _Float16*)(ws + CENO) + (size_t)b * IMG;
    const _Float16* botg = (const _Float16*)(ws + BOTO) + (size_t)b * IMG;

    half8v afr[2];
    #pragma unroll
    for (int kk = 0; kk < 2; ++kk)
        afr[kk] = *(const half8v*)&ceng[(size_t)(n0 + w * 16 + l16) * 64 + kk * 32 + quad * 8];

    int r0 = t >> 3, r1 = r0 + 32, off = (t & 7) * 8;
    int q2 = quad >> 1;
    int lpw = (w * 16 + quad * 4) * 72;
    int lpr = (w * 16 + l16) * 72;
    int rb3 = (l16 >> 3) & 1;

    f32x4 pv[4];
    #pragma unroll
    for (int j = 0; j < 4; ++j) pv[j] = (f32x4){0.f, 0.f, 0.f, 0.f};
    float runm = -3.0e38f, zacc = 0.f;

    int mp = s * 1024;
    half8v rt0 = *(const half8v*)&topg[(size_t)(mp + r0) * 64 + off];
    half8v rt1 = *(const half8v*)&topg[(size_t)(mp + r1) * 64 + off];
    half8v rb0 = *(const half8v*)&botg[(size_t)r0 * 4096 + mp + off];
    half8v rb1 = *(const half8v*)&botg[(size_t)r1 * 4096 + mp + off];

    for (int tt = 0; tt < 16; ++tt) {
        __syncthreads();
        *(half8v*)&ltop[r0 * 72 + off] = rt0;
        *(half8v*)&ltop[r1 * 72 + off] = rt1;
        *(half8v*)&lbot[r0 * 72 + off] = rb0;
        *(half8v*)&lbot[r1 * 72 + off] = rb1;
        __syncthreads();
        if (tt < 15) {
            int m1 = s * 1024 + (tt + 1) * 64;
            rt0 = *(const half8v*)&topg[(size_t)(m1 + r0) * 64 + off];
            rt1 = *(const half8v*)&topg[(size_t)(m1 + r1) * 64 + off];
            rb0 = *(const half8v*)&botg[(size_t)r0 * 4096 + m1 + off];
            rb1 = *(const half8v*)&botg[(size_t)r1 * 4096 + m1 + off];
        }
        f32x4 sa[4];
        #pragma unroll
        for (int j = 0; j < 4; ++j) sa[j] = (f32x4){0.f, 0.f, 0.f, 0.f};
        #pragma unroll
        for (int kk = 0; kk < 2; ++kk)
            #pragma unroll
            for (int j = 0; j < 4; ++j) {
                half8v bfr = *(half8v*)&ltop[(j * 16 + l16) * 72 + kk * 32 + quad * 8];
                sa[j] = __builtin_amdgcn_mfma_f32_16x16x32_f16(afr[kk], bfr, sa[j], 0, 0, 0);
            }
        float tm = -3.0e38f;
        #pragma unroll
        for (int j = 0; j < 4; ++j)
            #pragma unroll
            for (int r = 0; r < 4; ++r) tm = fmaxf(tm, sa[j][r]);
        for (int o2 = 32; o2; o2 >>= 1) tm = fmaxf(tm, __shfl_xor(tm, o2, 64));
        float newm = fmaxf(runm, tm);
        if (newm > runm) {
            float sc = exp2f(runm - newm);
            zacc *= sc;
            #pragma unroll
            for (int j = 0; j < 4; ++j) pv[j] *= sc;
            runm = newm;
        }
        #pragma unroll
        for (int j = 0; j < 4; ++j) {
            int cb = (j ^ q2) * 16 + l16;
            #pragma unroll
            for (int r = 0; r < 4; ++r) {
                float e = exp2f(sa[j][r] - runm);
                zacc += e;
                lp[lpw + r * 72 + cb] = (_Float16)e;
            }
        }
        half8v pa[2];
        #pragma unroll
        for (int kk = 0; kk < 2; ++kk) {
            int jj = kk * 2 + q2;
            pa[kk] = *(half8v*)&lp[lpr + ((jj ^ rb3) * 16) + (quad & 1) * 8];
        }
        #pragma unroll
        for (int kk = 0; kk < 2; ++kk)
            #pragma unroll
            for (int j = 0; j < 4; ++j) {
                half8v bb = *(half8v*)&lbot[(j * 16 + l16) * 72 + kk * 32 + quad * 8];
                pv[j] = __builtin_amdgcn_mfma_f32_16x16x32_f16(pa[kk], bb, pv[j], 0, 0, 0);
            }
    }
    for (int o2 = 32; o2; o2 >>= 1) zacc += __shfl_xor(zacc, o2, 64);
    if (lane == 0) {
        ws[MSO + s * 1024 + b * 256 + st * 4 + w] = runm;
        ws[ZSO + s * 1024 + b * 256 + st * 4 + w] = zacc;
    }
    short* pvp = (short*)(ws + PVO) + (size_t)s * 1048576 + (size_t)b * IMG;
    #pragma unroll
    for (int j = 0; j < 4; ++j)
        #pragma unroll
        for (int r = 0; r < 4; ++r)
            pvp[(size_t)(n0 + w * 16 + quad * 4 + r) * 64 + j * 16 + l16] = f2bf(pv[j][r]);
}

// Combine per-(split,16-row-group) (m_s, Z_s) -> global M, Z per batch. 1024 partials per b.
__global__ __launch_bounds__(256) void k_mz(float* __restrict__ ws) {
    int b = blockIdx.x, t = threadIdx.x;
    float mv[4];
    float m = -3.0e38f;
    #pragma unroll
    for (int s = 0; s < 4; ++s) {
        mv[s] = ws[MSO + s * 1024 + b * 256 + t];
        m = fmaxf(m, mv[s]);
    }
    for (int off = 32; off; off >>= 1) m = fmaxf(m, __shfl_xor(m, off, 64));
    __shared__ float rm[4], rz[4];
    if ((t & 63) == 0) rm[t >> 6] = m;
    __syncthreads();
    float M = fmaxf(fmaxf(rm[0], rm[1]), fmaxf(rm[2], rm[3]));
    float z = 0.f;
    #pragma unroll
    for (int s = 0; s < 4; ++s)
        z += ws[ZSO + s * 1024 + b * 256 + t] * exp2f(mv[s] - M);
    for (int off = 32; off; off >>= 1) z += __shfl_xor(z, off, 64);
    if ((t & 63) == 0) rz[t >> 6] = z;
    __syncthreads();
    if (t == 0) { ws[MO_ + b] = M; ws[ZO_ + b] = rz[0] + rz[1] + rz[2] + rz[3]; }
}

// u = x + softmax@bottom (flat add), then u-powers -> padded pixel-major fp16 (aliases xpad).
__global__ __launch_bounds__(256) void k_finalu(const float* __restrict__ x, float* __restrict__ ws,
                                                _Float16* __restrict__ upad) {
    __shared__ float us[64 * 65];
    int t = threadIdx.x, bx = blockIdx.x;
    int b = bx >> 6, h = bx & 63;
    float M = ws[MO_ + b], Z = ws[ZO_ + b];
    const short* pvb = (const short*)(ws + PVO) + (size_t)b * IMG;
    int hg = h >> 4;
    #pragma unroll
    for (int it = 0; it < 16; ++it) {
        int idx = it * 256 + t;
        int ci = idx >> 6, wc = idx & 63;
        int rem = ci * 4096 + h * 64 + wc;
        int grp = ci * 4 + hg;   // n = ci*64+h; 16-row group = n>>4
        float acc = 0.f;
        #pragma unroll
        for (int s = 0; s < MS; ++s) {
            float scl = exp2f(ws[MSO + s * 1024 + b * 256 + grp] - M);
            acc += bf2f(pvb[(size_t)s * 1048576 + rem]) * scl;
        }
        us[ci * 65 + wc] = x[(size_t)b * IMG + rem] + acc / Z;
    }
    __syncthreads();
    _Float16* dst = upad + ((size_t)b * PADIMG + (h + 1) * 66 + 1) * 192;
    #pragma unroll
    for (int it = 0; it < 48; ++it) {
        int idx = it * 256 + t;
        int m = idx / 192, k = idx - m * 192;
        int p = k >> 6, ci = k & 63;
        float v = us[ci * 65 + m];
        float pw = (p == 0) ? v : ((p == 1) ? v * v : v * v * v);
        dst[m * 192 + k] = (_Float16)pw;
    }
}

extern "C" void kernel_launch(void* const* d_in, const int* in_sizes, int n_in,
                              void* d_out, int out_size, void* d_ws, size_t ws_size,
                              hipStream_t stream) {
    (void)in_sizes; (void)n_in; (void)out_size; (void)ws_size;
    const float* x  = (const float*)d_in[0];
    const float* tw = (const float*)d_in[1];
    const float* tb = (const float*)d_in[2];
    const float* cw = (const float*)d_in[3];
    const float* cb = (const float*)d_in[4];
    const float* bw = (const float*)d_in[5];
    const float* bb = (const float*)d_in[6];
    const float* ow = (const float*)d_in[7];
    const float* ob = (const float*)d_in[8];
    float* ws  = (float*)d_ws;
    float* out = (float*)d_out;

    _Float16* wbf  = (_Float16*)(ws + WBFO);
    _Float16* wbot = wbf;
    _Float16* wout = wbf + 110592;
    _Float16* wtop = wbf + 221184;
    _Float16* wcen = wbf + 233472;
    _Float16* xpad = (_Float16*)(ws + XPADO);   // also upad (aliased)
    _Float16* topb = (_Float16*)(ws + TOPO);
    _Float16* cenb = (_Float16*)(ws + CENO);
    _Float16* botb = (_Float16*)(ws + BOTO);
    _Float16* part = (_Float16*)(ws + PVO);     // fp16 partials alias PV region

    hipMemsetAsync(xpad, 0, (size_t)3345408 * sizeof(_Float16), stream);  // zero padded borders
    hipLaunchKernelGGL(k_reorder, dim3(960), dim3(256), 0, stream, bw, ow, tw, cw, wbf);
    hipLaunchKernelGGL(k_pow, dim3(256), dim3(256), 0, stream, x, xpad);
    hipLaunchKernelGGL(k_conv1m, dim3(512), dim3(256), 0, stream, xpad, wtop, wcen, tb, cb, topb, cenb);
    hipLaunchKernelGGL(k_conv3m, dim3(1024), dim3(256), 0, stream, xpad, wbot, part);
    hipLaunchKernelGGL(k_combine, dim3(512), dim3(256), 0, stream, part, bb, botb, (float*)nullptr);
    hipLaunchKernelGGL(k_attn, dim3(1024), dim3(256), 0, stream, ws);
    hipLaunchKernelGGL(k_mz, dim3(4), dim3(256), 0, stream, ws);
    hipLaunchKernelGGL(k_finalu, dim3(256), dim3(256), 0, stream, x, ws, xpad);
    hipLaunchKernelGGL(k_conv3m, dim3(1024), dim3(256), 0, stream, xpad, wout, part);
    hipLaunchKernelGGL(k_combine, dim3(512), dim3(256), 0, stream, part, ob, (_Float16*)nullptr, out);
}

// Round 9
// 210.408 us; speedup vs baseline: 1.4411x; 1.0673x over previous
//
#include <hip/hip_runtime.h>
#include <hip/hip_bf16.h>

// Problem constants: B=4, C=64, H=W=64, HW=4096, P=64, Q=3 (CQ=192)
namespace {
constexpr int IMG    = 262144;   // 64*4096 elems per batch image
constexpr int MS     = 4;        // attention m-split
constexpr int PADIMG = 4356;     // 66*66 padded pixels
constexpr float LOG2E = 1.44269504088896340736f;
// workspace float offsets
constexpr int WBFO  = 0;         // fp16 weights: wbot[9][64][192], wout[9][64][192], wtop[64][192], wcen[64][192]
constexpr int XPADO = 122880;    // fp16 xp/up padded [4][4356][192] = 3345408 halfs (aliased: xp then up)
constexpr int TOPO  = 1795584;   // fp16 topT [b][m][p] = 1048576 halfs
constexpr int CENO  = 2319872;   // fp16 cenT [b][n][p]
constexpr int BOTO  = 2844160;   // fp16 bot  [b][c][m]
constexpr int PVO   = 3368448;   // bf16 PV [4][b][n][c] = 4194304 shorts
constexpr int MSO   = 5465600;   // m_s [s 4][b 4][group 256]  (group = 16-row n-group)
constexpr int ZSO   = 5469696;   // z_s  (MSO + 4096)
// total = 5473792 f = 20.9 MB
}

using half8v = __attribute__((ext_vector_type(8))) _Float16;
using half4v = __attribute__((ext_vector_type(4))) _Float16;
typedef __attribute__((ext_vector_type(4))) float f32x4;

__device__ __forceinline__ short f2bf(float f) {
    __hip_bfloat16 h = __float2bfloat16(f);
    return *reinterpret_cast<short*>(&h);
}
__device__ __forceinline__ float bf2f(short s) {
    unsigned u = ((unsigned)(unsigned short)s) << 16;
    return __uint_as_float(u);
}

// ---- Dispatch 1: weights->fp16 reorder (blocks 0..959) + x-powers into padded
// pixel-major xpad incl. border zeroing (blocks 960..1215). Replaces 3 dispatches.
__global__ __launch_bounds__(256) void k_prep(const float* __restrict__ bw, const float* __restrict__ ow,
                                              const float* __restrict__ tw, const float* __restrict__ cw,
                                              _Float16* __restrict__ wbf,
                                              const float* __restrict__ x, _Float16* __restrict__ xpad) {
    __shared__ float xs[64 * 65];
    int bx = blockIdx.x, t = threadIdx.x;
    if (bx < 960) {
        // weights: 3x3 w[o][(p*64+ci)*9+tap] -> wT[tap][o][p*64+ci]; 1x1 [o][192] cast.
        // Center weights pre-scaled by log2(e) (softmax in exp2 domain).
        int idx = bx * 256 + t;   // < 245760
        if (idx < 221184) {
            int tsel = idx / 110592;
            int r    = idx - tsel * 110592;
            int tap  = r / 12288;
            int rr   = r - tap * 12288;
            int o    = rr / 192;
            int i    = rr - o * 192;
            const float* src = tsel ? ow : bw;
            wbf[idx] = (_Float16)src[o * 1728 + i * 9 + tap];
        } else {
            int j = idx - 221184;
            int tsel = j / 12288;
            int rr   = j - tsel * 12288;
            wbf[idx] = (_Float16)(tsel ? cw[rr] * LOG2E : tw[rr]);
        }
        return;
    }
    int bx2 = bx - 960;
    int b = bx2 >> 6, h = bx2 & 63;
    // zero this block's share of the pad border (disjoint ownership; replaces memset)
    {
        _Float16* base = xpad + (size_t)b * PADIMG * 192;
        int px[6];
        px[0] = (h + 1) * 66;            // left col, this row
        px[1] = (h + 1) * 66 + 65;       // right col
        px[2] = h;                       // top row px h
        px[3] = 65 * 66 + h;             // bottom row px h
        int npx = 4;
        if (h < 2) { px[4] = 64 + h; px[5] = 65 * 66 + 64 + h; npx = 6; }
        int pi = t / 24, ck = t % 24;
        if (pi < npx) {
            half8v z = {0, 0, 0, 0, 0, 0, 0, 0};
            *(half8v*)&base[(size_t)px[pi] * 192 + ck * 8] = z;
        }
    }
    #pragma unroll
    for (int it = 0; it < 16; ++it) {
        int idx = it * 256 + t;
        int ci = idx >> 6, wc = idx & 63;
        xs[ci * 65 + wc] = x[b * IMG + ci * 4096 + h * 64 + wc];
    }
    __syncthreads();
    _Float16* dst = xpad + ((size_t)b * PADIMG + (h + 1) * 66 + 1) * 192;
    #pragma unroll
    for (int it = 0; it < 6; ++it) {
        int u = it * 256 + t;            // 0..1535: (px m, 8-half chunk ck)
        int m = u / 24, ck = u - m * 24;
        int k0 = ck * 8, p = k0 >> 6, c0 = k0 & 63;
        half8v o;
        #pragma unroll
        for (int j = 0; j < 8; ++j) {
            float v = xs[(c0 + j) * 65 + m];
            float pw = (p == 0) ? v : ((p == 1) ? v * v : v * v * v);
            o[j] = (_Float16)pw;
        }
        *(half8v*)&dst[m * 192 + k0] = o;
    }
}

// 3x3 SelfONN conv, full-K MFMA implicit GEMM, direct output + bias. No LDS.
// bx in [0,512): oh = bx>>8 (oc half), mt = bx&255 -> (b,h). Wave w: 16 px.
__device__ __forceinline__ void conv3_direct(int bx, int t,
                                             const _Float16* __restrict__ src,
                                             const _Float16* __restrict__ wt,
                                             const float* __restrict__ bias,
                                             _Float16* __restrict__ dh_, float* __restrict__ df) {
    int lane = t & 63, w = t >> 6;
    int l16 = lane & 15, quad = lane >> 4;
    int oh = bx >> 8, mt = bx & 255;
    int b = mt >> 6, h = mt & 63;
    const _Float16* abase = src + ((size_t)b * PADIMG + (h + 1) * 66 + (w * 16 + l16 + 1)) * 192 + quad * 8;
    const _Float16* bbase = wt + ((size_t)oh * 32 + l16) * 192 + quad * 8;
    f32x4 acc[2];
    acc[0] = (f32x4){0.f, 0.f, 0.f, 0.f};
    acc[1] = (f32x4){0.f, 0.f, 0.f, 0.f};
    for (int tap = 0; tap < 9; ++tap) {
        int dh = tap / 3 - 1, dw = tap % 3 - 1;
        const _Float16* arow = abase + (dh * 66 + dw) * 192;
        const _Float16* brow = bbase + (size_t)tap * 64 * 192;
        #pragma unroll
        for (int c6 = 0; c6 < 6; ++c6) {
            half8v afr = *(const half8v*)&arow[c6 * 32];
            #pragma unroll
            for (int nf = 0; nf < 2; ++nf) {
                half8v bfr = *(const half8v*)&brow[(size_t)(nf * 16) * 192 + c6 * 32];
                acc[nf] = __builtin_amdgcn_mfma_f32_16x16x32_f16(afr, bfr, acc[nf], 0, 0, 0);
            }
        }
    }
    #pragma unroll
    for (int nf = 0; nf < 2; ++nf) {
        int c = oh * 32 + nf * 16 + l16;
        float bv = bias[c];
        size_t oi = (size_t)b * 262144 + (size_t)c * 4096 + h * 64 + w * 16 + quad * 4;
        if (dh_) {
            half4v o;
            #pragma unroll
            for (int r = 0; r < 4; ++r) o[r] = (_Float16)(acc[nf][r] + bv);
            *(half4v*)&dh_[oi] = o;
        } else {
            float4 o = make_float4(acc[nf][0] + bv, acc[nf][1] + bv, acc[nf][2] + bv, acc[nf][3] + bv);
            *(float4*)&df[oi] = o;
        }
    }
}

// ---- Dispatch 2: conv3-bottom (blocks 0..511, direct fp16 out) + fused
// top/center 1x1 convs (blocks 512..1023). Replaces 3 dispatches.
__global__ __launch_bounds__(256) void k_convs(const _Float16* __restrict__ xpad,
                                               const _Float16* __restrict__ wbf,
                                               const float* __restrict__ tb, const float* __restrict__ cb,
                                               const float* __restrict__ bbias,
                                               _Float16* __restrict__ topd, _Float16* __restrict__ cend,
                                               _Float16* __restrict__ botb) {
    int bx = blockIdx.x, t = threadIdx.x;
    if (bx < 512) {
        conv3_direct(bx, t, xpad, wbf /* wbot at offset 0 */, bbias, botb, nullptr);
        return;
    }
    int bx2 = bx - 512;
    int lane = t & 63, w = t >> 6;
    int l16 = lane & 15, quad = lane >> 4;
    int ot = bx2 >> 8, mt = bx2 & 255;
    int b = mt >> 6, h = mt & 63;
    const _Float16* wt   = wbf + (ot ? 233472 : 221184);   // wcen : wtop
    const float*    bias = ot ? cb : tb;
    _Float16*       dst  = (ot ? cend : topd) + (size_t)b * IMG;
    const _Float16* abase = xpad + ((size_t)b * PADIMG + (h + 1) * 66 + (w * 16 + l16 + 1)) * 192 + quad * 8;
    const _Float16* bbase = wt + l16 * 192 + quad * 8;
    f32x4 acc[4];
    #pragma unroll
    for (int nf = 0; nf < 4; ++nf) acc[nf] = (f32x4){0.f, 0.f, 0.f, 0.f};
    #pragma unroll
    for (int kc = 0; kc < 6; ++kc) {
        half8v afr = *(const half8v*)&abase[kc * 32];
        #pragma unroll
        for (int nf = 0; nf < 4; ++nf) {
            half8v bfr = *(const half8v*)&bbase[nf * 16 * 192 + kc * 32];
            acc[nf] = __builtin_amdgcn_mfma_f32_16x16x32_f16(afr, bfr, acc[nf], 0, 0, 0);
        }
    }
    _Float16* dp = dst + (size_t)(h * 64 + w * 16) * 64;
    #pragma unroll
    for (int nf = 0; nf < 4; ++nf) {
        float bv = bias[nf * 16 + l16];
        if (ot) bv *= LOG2E;   // center output lives in log2e-scaled domain
        #pragma unroll
        for (int r = 0; r < 4; ++r)
            dp[(quad * 4 + r) * 64 + nf * 16 + l16] = (_Float16)(acc[nf][r] + bv);
    }
}

// ---- Dispatch 3: fp16 MFMA flash attention, global softmax, per-wave online max.
// LDS staging + register prefetch pipeline; lp wave-private + XOR swizzle.
// grid 1024: (strip 64) x (b 4) x (split 4).
__global__ __launch_bounds__(256, 4) void k_attn(float* __restrict__ ws) {
    __shared__ _Float16 ltop[64 * 72];   // [m][p]
    __shared__ _Float16 lbot[64 * 72];   // [c][m]
    __shared__ _Float16 lp[64 * 72];     // [n][m swizzled]; wave-private rows
    int t    = threadIdx.x;
    int lane = t & 63, w = t >> 6;
    int l16  = lane & 15, quad = lane >> 4;
    int bx = blockIdx.x;
    int st = bx & 63, b = (bx >> 6) & 3, s = bx >> 8;
    int n0 = st * 64;
    const _Float16* topg = (const _Float16*)(ws + TOPO) + (size_t)b * IMG;
    const _Float16* ceng = (const _Float16*)(ws + CENO) + (size_t)b * IMG;
    const _Float16* botg = (const _Float16*)(ws + BOTO) + (size_t)b * IMG;

    half8v afr[2];
    #pragma unroll
    for (int kk = 0; kk < 2; ++kk)
        afr[kk] = *(const half8v*)&ceng[(size_t)(n0 + w * 16 + l16) * 64 + kk * 32 + quad * 8];

    int r0 = t >> 3, r1 = r0 + 32, off = (t & 7) * 8;
    int q2 = quad >> 1;
    int lpw = (w * 16 + quad * 4) * 72;
    int lpr = (w * 16 + l16) * 72;
    int rb3 = (l16 >> 3) & 1;

    f32x4 pv[4];
    #pragma unroll
    for (int j = 0; j < 4; ++j) pv[j] = (f32x4){0.f, 0.f, 0.f, 0.f};
    float runm = -3.0e38f, zacc = 0.f;

    int mp = s * 1024;
    half8v rt0 = *(const half8v*)&topg[(size_t)(mp + r0) * 64 + off];
    half8v rt1 = *(const half8v*)&topg[(size_t)(mp + r1) * 64 + off];
    half8v rb0 = *(const half8v*)&botg[(size_t)r0 * 4096 + mp + off];
    half8v rb1 = *(const half8v*)&botg[(size_t)r1 * 4096 + mp + off];

    for (int tt = 0; tt < 16; ++tt) {
        __syncthreads();
        *(half8v*)&ltop[r0 * 72 + off] = rt0;
        *(half8v*)&ltop[r1 * 72 + off] = rt1;
        *(half8v*)&lbot[r0 * 72 + off] = rb0;
        *(half8v*)&lbot[r1 * 72 + off] = rb1;
        __syncthreads();
        if (tt < 15) {
            int m1 = s * 1024 + (tt + 1) * 64;
            rt0 = *(const half8v*)&topg[(size_t)(m1 + r0) * 64 + off];
            rt1 = *(const half8v*)&topg[(size_t)(m1 + r1) * 64 + off];
            rb0 = *(const half8v*)&botg[(size_t)r0 * 4096 + m1 + off];
            rb1 = *(const half8v*)&botg[(size_t)r1 * 4096 + m1 + off];
        }
        f32x4 sa[4];
        #pragma unroll
        for (int j = 0; j < 4; ++j) sa[j] = (f32x4){0.f, 0.f, 0.f, 0.f};
        #pragma unroll
        for (int kk = 0; kk < 2; ++kk)
            #pragma unroll
            for (int j = 0; j < 4; ++j) {
                half8v bfr = *(half8v*)&ltop[(j * 16 + l16) * 72 + kk * 32 + quad * 8];
                sa[j] = __builtin_amdgcn_mfma_f32_16x16x32_f16(afr[kk], bfr, sa[j], 0, 0, 0);
            }
        float tm = -3.0e38f;
        #pragma unroll
        for (int j = 0; j < 4; ++j)
            #pragma unroll
            for (int r = 0; r < 4; ++r) tm = fmaxf(tm, sa[j][r]);
        for (int o2 = 32; o2; o2 >>= 1) tm = fmaxf(tm, __shfl_xor(tm, o2, 64));
        float newm = fmaxf(runm, tm);
        if (newm > runm) {
            float sc = exp2f(runm - newm);
            zacc *= sc;
            #pragma unroll
            for (int j = 0; j < 4; ++j) pv[j] *= sc;
            runm = newm;
        }
        #pragma unroll
        for (int j = 0; j < 4; ++j) {
            int cb = (j ^ q2) * 16 + l16;
            #pragma unroll
            for (int r = 0; r < 4; ++r) {
                float e = exp2f(sa[j][r] - runm);
                zacc += e;
                lp[lpw + r * 72 + cb] = (_Float16)e;
            }
        }
        half8v pa[2];
        #pragma unroll
        for (int kk = 0; kk < 2; ++kk) {
            int jj = kk * 2 + q2;
            pa[kk] = *(half8v*)&lp[lpr + ((jj ^ rb3) * 16) + (quad & 1) * 8];
        }
        #pragma unroll
        for (int kk = 0; kk < 2; ++kk)
            #pragma unroll
            for (int j = 0; j < 4; ++j) {
                half8v bb = *(half8v*)&lbot[(j * 16 + l16) * 72 + kk * 32 + quad * 8];
                pv[j] = __builtin_amdgcn_mfma_f32_16x16x32_f16(pa[kk], bb, pv[j], 0, 0, 0);
            }
    }
    for (int o2 = 32; o2; o2 >>= 1) zacc += __shfl_xor(zacc, o2, 64);
    if (lane == 0) {
        ws[MSO + s * 1024 + b * 256 + st * 4 + w] = runm;
        ws[ZSO + s * 1024 + b * 256 + st * 4 + w] = zacc;
    }
    short* pvp = (short*)(ws + PVO) + (size_t)s * 1048576 + (size_t)b * IMG;
    #pragma unroll
    for (int j = 0; j < 4; ++j)
        #pragma unroll
        for (int r = 0; r < 4; ++r)
            pvp[(size_t)(n0 + w * 16 + quad * 4 + r) * 64 + j * 16 + l16] = f2bf(pv[j][r]);
}

// ---- Dispatch 4: inline M/Z reduction (was k_mz) + u = x + softmax@bottom +
// u-powers -> padded pixel-major fp16 (aliases xpad). Replaces 2 dispatches.
__global__ __launch_bounds__(256) void k_finalu(const float* __restrict__ x, float* __restrict__ ws,
                                                _Float16* __restrict__ upad) {
    __shared__ float us[64 * 65];
    __shared__ float rm[4], rz[4];
    int t = threadIdx.x, bx = blockIdx.x;
    int b = bx >> 6, h = bx & 63;
    // inline M,Z: thread t owns group t of batch b (redundant per block, parallel)
    float mv[4];
    float m = -3.0e38f;
    #pragma unroll
    for (int s = 0; s < 4; ++s) {
        mv[s] = ws[MSO + s * 1024 + b * 256 + t];
        m = fmaxf(m, mv[s]);
    }
    for (int o2 = 32; o2; o2 >>= 1) m = fmaxf(m, __shfl_xor(m, o2, 64));
    if ((t & 63) == 0) rm[t >> 6] = m;
    __syncthreads();
    float M = fmaxf(fmaxf(rm[0], rm[1]), fmaxf(rm[2], rm[3]));
    float z = 0.f;
    #pragma unroll
    for (int s = 0; s < 4; ++s)
        z += ws[ZSO + s * 1024 + b * 256 + t] * exp2f(mv[s] - M);
    for (int o2 = 32; o2; o2 >>= 1) z += __shfl_xor(z, o2, 64);
    if ((t & 63) == 0) rz[t >> 6] = z;
    __syncthreads();
    float Z = rz[0] + rz[1] + rz[2] + rz[3];

    const short* pvb = (const short*)(ws + PVO) + (size_t)b * IMG;
    int hg = h >> 4;
    #pragma unroll
    for (int it = 0; it < 16; ++it) {
        int idx = it * 256 + t;
        int ci = idx >> 6, wc = idx & 63;
        int rem = ci * 4096 + h * 64 + wc;
        int grp = ci * 4 + hg;   // n = ci*64+h; 16-row group = n>>4
        float acc = 0.f;
        #pragma unroll
        for (int s = 0; s < MS; ++s) {
            float scl = exp2f(ws[MSO + s * 1024 + b * 256 + grp] - M);
            acc += bf2f(pvb[(size_t)s * 1048576 + rem]) * scl;
        }
        us[ci * 65 + wc] = x[(size_t)b * IMG + rem] + acc / Z;
    }
    __syncthreads();
    _Float16* dst = upad + ((size_t)b * PADIMG + (h + 1) * 66 + 1) * 192;
    #pragma unroll
    for (int it = 0; it < 6; ++it) {
        int u = it * 256 + t;            // 0..1535
        int m2 = u / 24, ck = u - m2 * 24;
        int k0 = ck * 8, p = k0 >> 6, c0 = k0 & 63;
        half8v o;
        #pragma unroll
        for (int j = 0; j < 8; ++j) {
            float v = us[(c0 + j) * 65 + m2];
            float pw = (p == 0) ? v : ((p == 1) ? v * v : v * v * v);
            o[j] = (_Float16)pw;
        }
        *(half8v*)&dst[m2 * 192 + k0] = o;
    }
}

// ---- Dispatch 5: final 3x3 conv, direct fp32 output + bias.
__global__ __launch_bounds__(256) void k_conv3o(const _Float16* __restrict__ upad,
                                                const _Float16* __restrict__ wout,
                                                const float* __restrict__ ob,
                                                float* __restrict__ out) {
    conv3_direct(blockIdx.x, threadIdx.x, upad, wout, ob, nullptr, out);
}

extern "C" void kernel_launch(void* const* d_in, const int* in_sizes, int n_in,
                              void* d_out, int out_size, void* d_ws, size_t ws_size,
                              hipStream_t stream) {
    (void)in_sizes; (void)n_in; (void)out_size; (void)ws_size;
    const float* x  = (const float*)d_in[0];
    const float* tw = (const float*)d_in[1];
    const float* tb = (const float*)d_in[2];
    const float* cw = (const float*)d_in[3];
    const float* cb = (const float*)d_in[4];
    const float* bw = (const float*)d_in[5];
    const float* bb = (const float*)d_in[6];
    const float* ow = (const float*)d_in[7];
    const float* ob = (const float*)d_in[8];
    float* ws  = (float*)d_ws;
    float* out = (float*)d_out;

    _Float16* wbf  = (_Float16*)(ws + WBFO);
    _Float16* wout = wbf + 110592;
    _Float16* xpad = (_Float16*)(ws + XPADO);   // also upad (aliased)
    _Float16* topb = (_Float16*)(ws + TOPO);
    _Float16* cenb = (_Float16*)(ws + CENO);
    _Float16* botb = (_Float16*)(ws + BOTO);

    hipLaunchKernelGGL(k_prep, dim3(1216), dim3(256), 0, stream, bw, ow, tw, cw, wbf, x, xpad);
    hipLaunchKernelGGL(k_convs, dim3(1024), dim3(256), 0, stream, xpad, wbf, tb, cb, bb, topb, cenb, botb);
    hipLaunchKernelGGL(k_attn, dim3(1024), dim3(256), 0, stream, ws);
    hipLaunchKernelGGL(k_finalu, dim3(256), dim3(256), 0, stream, x, ws, xpad);
    hipLaunchKernelGGL(k_conv3o, dim3(512), dim3(256), 0, stream, xpad, wout, ob, out);
}

// Round 10
// 183.048 us; speedup vs baseline: 1.6566x; 1.1495x over previous
//
#include <hip/hip_runtime.h>
#include <hip/hip_bf16.h>

// Problem constants: B=4, C=64, H=W=64, HW=4096, P=64, Q=3 (CQ=192)
namespace {
constexpr int IMG    = 262144;   // 64*4096 elems per batch image
constexpr int MS     = 4;        // attention m-split
constexpr int PADIMG = 4356;     // 66*66 padded pixels
constexpr float LOG2E = 1.44269504088896340736f;
// workspace float offsets
constexpr int WBFO  = 0;         // fp16 weights: wbot[9][6][64][32], wout[9][6][64][32], wtop[6][64][32], wcen[6][64][32]
constexpr int XPADO = 122880;    // fp16 xp/up padded [b][ck 6][px 4356][32] = 3345408 halfs (aliased: xp then up)
constexpr int TOPO  = 1795584;   // fp16 topT [b][m][p] = 1048576 halfs
constexpr int CENO  = 2319872;   // fp16 cenT [b][n][p]
constexpr int BOTO  = 2844160;   // fp16 bot  [b][c][m]
constexpr int PVO   = 3368448;   // bf16 PV [4][b][n][c] = 4194304 shorts
constexpr int MSO   = 5465600;   // m_s [s 4][b 4][group 256]  (group = 16-row n-group)
constexpr int ZSO   = 5469696;   // z_s  (MSO + 4096)
// total = 5473792 f = 20.9 MB
}

using half8v = __attribute__((ext_vector_type(8))) _Float16;
using half4v = __attribute__((ext_vector_type(4))) _Float16;
typedef __attribute__((ext_vector_type(4))) float f32x4;

__device__ __forceinline__ short f2bf(float f) {
    __hip_bfloat16 h = __float2bfloat16(f);
    return *reinterpret_cast<short*>(&h);
}
__device__ __forceinline__ float bf2f(short s) {
    unsigned u = ((unsigned)(unsigned short)s) << 16;
    return __uint_as_float(u);
}

// ---- Dispatch 1: weights->fp16 reorder into k-chunked layouts (blocks 0..959)
// + x-powers into chunked padded xpad incl. border zeroing (blocks 960..1215).
__global__ __launch_bounds__(256) void k_prep(const float* __restrict__ bw, const float* __restrict__ ow,
                                              const float* __restrict__ tw, const float* __restrict__ cw,
                                              _Float16* __restrict__ wbf,
                                              const float* __restrict__ x, _Float16* __restrict__ xpad) {
    __shared__ float xs[64 * 65];
    int bx = blockIdx.x, t = threadIdx.x;
    if (bx < 960) {
        int idx = bx * 256 + t;   // < 245760
        if (idx < 221184) {
            // 3x3: w[o][(p*64+ci)*9+tap] -> wT[tap][ck][o][ki]  (k = ck*32+ki = p*64+ci)
            int tsel = idx / 110592;
            int r    = idx - tsel * 110592;
            int tap  = r / 12288;
            int rr   = r - tap * 12288;
            int ck   = rr / 2048;
            int r2   = rr - ck * 2048;
            int o    = r2 >> 5;
            int ki   = r2 & 31;
            int k    = ck * 32 + ki;
            int p    = k >> 6, ci = k & 63;
            const float* src = tsel ? ow : bw;
            wbf[idx] = (_Float16)src[o * 1728 + (p * 64 + ci) * 9 + tap];
        } else {
            // 1x1: w[o][192] -> wT[ck][o][ki]; center pre-scaled by log2(e)
            int j = idx - 221184;
            int tsel = j / 12288;
            int rr   = j - tsel * 12288;
            int ck   = rr / 2048;
            int r2   = rr - ck * 2048;
            int o    = r2 >> 5;
            int ki   = r2 & 31;
            int k    = ck * 32 + ki;
            wbf[idx] = (_Float16)(tsel ? cw[o * 192 + k] * LOG2E : tw[o * 192 + k]);
        }
        return;
    }
    int bx2 = bx - 960;
    int b = bx2 >> 6, h = bx2 & 63;
    // zero this block's share of the pad border across all 6 chunk planes
    {
        _Float16* base = xpad + (size_t)b * 6 * PADIMG * 32;
        int px[6];
        px[0] = (h + 1) * 66;            // left col, this row
        px[1] = (h + 1) * 66 + 65;       // right col
        px[2] = h;                       // top row px h
        px[3] = 65 * 66 + h;             // bottom row px h
        int npx = 4;
        if (h < 2) { px[4] = 64 + h; px[5] = 65 * 66 + 64 + h; npx = 6; }
        int pi = t / 24, ck = t % 24;    // ck: 6 chunks x 4 quads
        if (pi < npx) {
            int cp = ck >> 2, q = ck & 3;
            half8v z = {0, 0, 0, 0, 0, 0, 0, 0};
            *(half8v*)&base[((size_t)cp * PADIMG + px[pi]) * 32 + q * 8] = z;
        }
    }
    #pragma unroll
    for (int it = 0; it < 16; ++it) {
        int idx = it * 256 + t;
        int ci = idx >> 6, wc = idx & 63;
        xs[ci * 65 + wc] = x[b * IMG + ci * 4096 + h * 64 + wc];
    }
    __syncthreads();
    _Float16* dst = xpad + ((size_t)b * 6 * PADIMG + (h + 1) * 66 + 1) * 32;
    #pragma unroll
    for (int it = 0; it < 6; ++it) {
        int u = it * 256 + t;            // 0..1535: ck plane, px, quad
        int ck = u >> 8, within = u & 255;
        int px = within >> 2, q = within & 3;
        int k0 = ck * 32 + q * 8;
        int p = k0 >> 6, c0 = k0 & 63;   // 8 consecutive k share p (no 64-cross)
        half8v o;
        #pragma unroll
        for (int j = 0; j < 8; ++j) {
            float v = xs[(c0 + j) * 65 + px];
            float pw = (p == 0) ? v : ((p == 1) ? v * v : v * v * v);
            o[j] = (_Float16)pw;
        }
        *(half8v*)&dst[((size_t)ck * PADIMG + px) * 32 + q * 8] = o;
    }
}

// 3x3 SelfONN conv, full-K MFMA implicit GEMM, direct output + bias. No LDS.
// bx in [0,1024): oh = bx>>8 (oc quarter, 16 oc), mt = bx&255 -> (b,h).
// All fragment loads fully coalesced (1KB/wave contiguous) via chunked layouts.
__device__ __forceinline__ void conv3_direct(int bx, int t,
                                             const _Float16* __restrict__ src,
                                             const _Float16* __restrict__ wt,
                                             const float* __restrict__ bias,
                                             _Float16* __restrict__ dh_, float* __restrict__ df) {
    int lane = t & 63, w = t >> 6;
    int l16 = lane & 15, quad = lane >> 4;
    int oh = bx >> 8, mt = bx & 255;
    int b = mt >> 6, h = mt & 63;
    const _Float16* abase = src + ((size_t)b * 6 * PADIMG + (h + 1) * 66 + 1 + w * 16 + l16) * 32 + quad * 8;
    const _Float16* bbase = wt + (size_t)(oh * 16 + l16) * 32 + quad * 8;
    f32x4 acc = (f32x4){0.f, 0.f, 0.f, 0.f};
    for (int tap = 0; tap < 9; ++tap) {
        int dh = tap / 3 - 1, dw = tap % 3 - 1;
        const _Float16* arow = abase + (dh * 66 + dw) * 32;
        const _Float16* brow = bbase + (size_t)tap * 6 * 2048;
        #pragma unroll
        for (int c6 = 0; c6 < 6; ++c6) {
            half8v afr = *(const half8v*)&arow[(size_t)c6 * PADIMG * 32];
            half8v bfr = *(const half8v*)&brow[(size_t)c6 * 2048];
            acc = __builtin_amdgcn_mfma_f32_16x16x32_f16(afr, bfr, acc, 0, 0, 0);
        }
    }
    int c = oh * 16 + l16;
    float bv = bias[c];
    size_t oi = (size_t)b * 262144 + (size_t)c * 4096 + h * 64 + w * 16 + quad * 4;
    if (dh_) {
        half4v o;
        #pragma unroll
        for (int r = 0; r < 4; ++r) o[r] = (_Float16)(acc[r] + bv);
        *(half4v*)&dh_[oi] = o;
    } else {
        float4 o = make_float4(acc[0] + bv, acc[1] + bv, acc[2] + bv, acc[3] + bv);
        *(float4*)&df[oi] = o;
    }
}

// ---- Dispatch 2: conv3-bottom (blocks 0..1023, direct fp16 out) + fused
// top/center 1x1 convs (blocks 1024..1535).
__global__ __launch_bounds__(256) void k_convs(const _Float16* __restrict__ xpad,
                                               const _Float16* __restrict__ wbf,
                                               const float* __restrict__ tb, const float* __restrict__ cb,
                                               const float* __restrict__ bbias,
                                               _Float16* __restrict__ topd, _Float16* __restrict__ cend,
                                               _Float16* __restrict__ botb) {
    int bx = blockIdx.x, t = threadIdx.x;
    if (bx < 1024) {
        conv3_direct(bx, t, xpad, wbf /* wbot at offset 0 */, bbias, botb, nullptr);
        return;
    }
    int bx2 = bx - 1024;
    int lane = t & 63, w = t >> 6;
    int l16 = lane & 15, quad = lane >> 4;
    int ot = bx2 >> 8, mt = bx2 & 255;
    int b = mt >> 6, h = mt & 63;
    const _Float16* wt   = wbf + (ot ? 233472 : 221184);   // wcen : wtop
    const float*    bias = ot ? cb : tb;
    _Float16*       dst  = (ot ? cend : topd) + (size_t)b * IMG;
    const _Float16* abase = xpad + ((size_t)b * 6 * PADIMG + (h + 1) * 66 + 1 + w * 16 + l16) * 32 + quad * 8;
    const _Float16* bbase = wt + (size_t)l16 * 32 + quad * 8;
    f32x4 acc[4];
    #pragma unroll
    for (int nf = 0; nf < 4; ++nf) acc[nf] = (f32x4){0.f, 0.f, 0.f, 0.f};
    #pragma unroll
    for (int kc = 0; kc < 6; ++kc) {
        half8v afr = *(const half8v*)&abase[(size_t)kc * PADIMG * 32];
        #pragma unroll
        for (int nf = 0; nf < 4; ++nf) {
            half8v bfr = *(const half8v*)&bbase[(size_t)kc * 2048 + nf * 16 * 32];
            acc[nf] = __builtin_amdgcn_mfma_f32_16x16x32_f16(afr, bfr, acc[nf], 0, 0, 0);
        }
    }
    _Float16* dp = dst + (size_t)(h * 64 + w * 16) * 64;
    #pragma unroll
    for (int nf = 0; nf < 4; ++nf) {
        float bv = bias[nf * 16 + l16];
        if (ot) bv *= LOG2E;   // center output lives in log2e-scaled domain
        #pragma unroll
        for (int r = 0; r < 4; ++r)
            dp[(quad * 4 + r) * 64 + nf * 16 + l16] = (_Float16)(acc[nf][r] + bv);
    }
}

// ---- Dispatch 3: fp16 MFMA flash attention, global softmax, per-wave online max.
// LDS staging + register prefetch pipeline; lp wave-private + XOR swizzle.
// grid 1024: (strip 64) x (b 4) x (split 4).
__global__ __launch_bounds__(256, 4) void k_attn(float* __restrict__ ws) {
    __shared__ _Float16 ltop[64 * 72];   // [m][p]
    __shared__ _Float16 lbot[64 * 72];   // [c][m]
    __shared__ _Float16 lp[64 * 72];     // [n][m swizzled]; wave-private rows
    int t    = threadIdx.x;
    int lane = t & 63, w = t >> 6;
    int l16  = lane & 15, quad = lane >> 4;
    int bx = blockIdx.x;
    int st = bx & 63, b = (bx >> 6) & 3, s = bx >> 8;
    int n0 = st * 64;
    const _Float16* topg = (const _Float16*)(ws + TOPO) + (size_t)b * IMG;
    const _Float16* ceng = (const _Float16*)(ws + CENO) + (size_t)b * IMG;
    const _Float16* botg = (const _Float16*)(ws + BOTO) + (size_t)b * IMG;

    half8v afr[2];
    #pragma unroll
    for (int kk = 0; kk < 2; ++kk)
        afr[kk] = *(const half8v*)&ceng[(size_t)(n0 + w * 16 + l16) * 64 + kk * 32 + quad * 8];

    int r0 = t >> 3, r1 = r0 + 32, off = (t & 7) * 8;
    int q2 = quad >> 1;
    int lpw = (w * 16 + quad * 4) * 72;
    int lpr = (w * 16 + l16) * 72;
    int rb3 = (l16 >> 3) & 1;

    f32x4 pv[4];
    #pragma unroll
    for (int j = 0; j < 4; ++j) pv[j] = (f32x4){0.f, 0.f, 0.f, 0.f};
    float runm = -3.0e38f, zacc = 0.f;

    int mp = s * 1024;
    half8v rt0 = *(const half8v*)&topg[(size_t)(mp + r0) * 64 + off];
    half8v rt1 = *(const half8v*)&topg[(size_t)(mp + r1) * 64 + off];
    half8v rb0 = *(const half8v*)&botg[(size_t)r0 * 4096 + mp + off];
    half8v rb1 = *(const half8v*)&botg[(size_t)r1 * 4096 + mp + off];

    for (int tt = 0; tt < 16; ++tt) {
        __syncthreads();
        *(half8v*)&ltop[r0 * 72 + off] = rt0;
        *(half8v*)&ltop[r1 * 72 + off] = rt1;
        *(half8v*)&lbot[r0 * 72 + off] = rb0;
        *(half8v*)&lbot[r1 * 72 + off] = rb1;
        __syncthreads();
        if (tt < 15) {
            int m1 = s * 1024 + (tt + 1) * 64;
            rt0 = *(const half8v*)&topg[(size_t)(m1 + r0) * 64 + off];
            rt1 = *(const half8v*)&topg[(size_t)(m1 + r1) * 64 + off];
            rb0 = *(const half8v*)&botg[(size_t)r0 * 4096 + m1 + off];
            rb1 = *(const half8v*)&botg[(size_t)r1 * 4096 + m1 + off];
        }
        f32x4 sa[4];
        #pragma unroll
        for (int j = 0; j < 4; ++j) sa[j] = (f32x4){0.f, 0.f, 0.f, 0.f};
        #pragma unroll
        for (int kk = 0; kk < 2; ++kk)
            #pragma unroll
            for (int j = 0; j < 4; ++j) {
                half8v bfr = *(half8v*)&ltop[(j * 16 + l16) * 72 + kk * 32 + quad * 8];
                sa[j] = __builtin_amdgcn_mfma_f32_16x16x32_f16(afr[kk], bfr, sa[j], 0, 0, 0);
            }
        float tm = -3.0e38f;
        #pragma unroll
        for (int j = 0; j < 4; ++j)
            #pragma unroll
            for (int r = 0; r < 4; ++r) tm = fmaxf(tm, sa[j][r]);
        for (int o2 = 32; o2; o2 >>= 1) tm = fmaxf(tm, __shfl_xor(tm, o2, 64));
        float newm = fmaxf(runm, tm);
        if (newm > runm) {
            float sc = exp2f(runm - newm);
            zacc *= sc;
            #pragma unroll
            for (int j = 0; j < 4; ++j) pv[j] *= sc;
            runm = newm;
        }
        #pragma unroll
        for (int j = 0; j < 4; ++j) {
            int cb = (j ^ q2) * 16 + l16;
            #pragma unroll
            for (int r = 0; r < 4; ++r) {
                float e = exp2f(sa[j][r] - runm);
                zacc += e;
                lp[lpw + r * 72 + cb] = (_Float16)e;
            }
        }
        half8v pa[2];
        #pragma unroll
        for (int kk = 0; kk < 2; ++kk) {
            int jj = kk * 2 + q2;
            pa[kk] = *(half8v*)&lp[lpr + ((jj ^ rb3) * 16) + (quad & 1) * 8];
        }
        #pragma unroll
        for (int kk = 0; kk < 2; ++kk)
            #pragma unroll
            for (int j = 0; j < 4; ++j) {
                half8v bb = *(half8v*)&lbot[(j * 16 + l16) * 72 + kk * 32 + quad * 8];
                pv[j] = __builtin_amdgcn_mfma_f32_16x16x32_f16(pa[kk], bb, pv[j], 0, 0, 0);
            }
    }
    for (int o2 = 32; o2; o2 >>= 1) zacc += __shfl_xor(zacc, o2, 64);
    if (lane == 0) {
        ws[MSO + s * 1024 + b * 256 + st * 4 + w] = runm;
        ws[ZSO + s * 1024 + b * 256 + st * 4 + w] = zacc;
    }
    short* pvp = (short*)(ws + PVO) + (size_t)s * 1048576 + (size_t)b * IMG;
    #pragma unroll
    for (int j = 0; j < 4; ++j)
        #pragma unroll
        for (int r = 0; r < 4; ++r)
            pvp[(size_t)(n0 + w * 16 + quad * 4 + r) * 64 + j * 16 + l16] = f2bf(pv[j][r]);
}

// ---- Dispatch 4: inline M/Z reduction + u = x + softmax@bottom + u-powers ->
// chunked padded fp16 (aliases xpad).
__global__ __launch_bounds__(256) void k_finalu(const float* __restrict__ x, float* __restrict__ ws,
                                                _Float16* __restrict__ upad) {
    __shared__ float us[64 * 65];
    __shared__ float rm[4], rz[4];
    int t = threadIdx.x, bx = blockIdx.x;
    int b = bx >> 6, h = bx & 63;
    float mv[4];
    float m = -3.0e38f;
    #pragma unroll
    for (int s = 0; s < 4; ++s) {
        mv[s] = ws[MSO + s * 1024 + b * 256 + t];
        m = fmaxf(m, mv[s]);
    }
    for (int o2 = 32; o2; o2 >>= 1) m = fmaxf(m, __shfl_xor(m, o2, 64));
    if ((t & 63) == 0) rm[t >> 6] = m;
    __syncthreads();
    float M = fmaxf(fmaxf(rm[0], rm[1]), fmaxf(rm[2], rm[3]));
    float z = 0.f;
    #pragma unroll
    for (int s = 0; s < 4; ++s)
        z += ws[ZSO + s * 1024 + b * 256 + t] * exp2f(mv[s] - M);
    for (int o2 = 32; o2; o2 >>= 1) z += __shfl_xor(z, o2, 64);
    if ((t & 63) == 0) rz[t >> 6] = z;
    __syncthreads();
    float Z = rz[0] + rz[1] + rz[2] + rz[3];

    const short* pvb = (const short*)(ws + PVO) + (size_t)b * IMG;
    int hg = h >> 4;
    #pragma unroll
    for (int it = 0; it < 16; ++it) {
        int idx = it * 256 + t;
        int ci = idx >> 6, wc = idx & 63;
        int rem = ci * 4096 + h * 64 + wc;
        int grp = ci * 4 + hg;   // n = ci*64+h; 16-row group = n>>4
        float acc = 0.f;
        #pragma unroll
        for (int s = 0; s < MS; ++s) {
            float scl = exp2f(ws[MSO + s * 1024 + b * 256 + grp] - M);
            acc += bf2f(pvb[(size_t)s * 1048576 + rem]) * scl;
        }
        us[ci * 65 + wc] = x[(size_t)b * IMG + rem] + acc / Z;
    }
    __syncthreads();
    _Float16* dst = upad + ((size_t)b * 6 * PADIMG + (h + 1) * 66 + 1) * 32;
    #pragma unroll
    for (int it = 0; it < 6; ++it) {
        int u = it * 256 + t;
        int ck = u >> 8, within = u & 255;
        int px = within >> 2, q = within & 3;
        int k0 = ck * 32 + q * 8;
        int p = k0 >> 6, c0 = k0 & 63;
        half8v o;
        #pragma unroll
        for (int j = 0; j < 8; ++j) {
            float v = us[(c0 + j) * 65 + px];
            float pw = (p == 0) ? v : ((p == 1) ? v * v : v * v * v);
            o[j] = (_Float16)pw;
        }
        *(half8v*)&dst[((size_t)ck * PADIMG + px) * 32 + q * 8] = o;
    }
}

// ---- Dispatch 5: final 3x3 conv, direct fp32 output + bias. grid 1024.
__global__ __launch_bounds__(256) void k_conv3o(const _Float16* __restrict__ upad,
                                                const _Float16* __restrict__ wout,
                                                const float* __restrict__ ob,
                                                float* __restrict__ out) {
    conv3_direct(blockIdx.x, threadIdx.x, upad, wout, ob, nullptr, out);
}

extern "C" void kernel_launch(void* const* d_in, const int* in_sizes, int n_in,
                              void* d_out, int out_size, void* d_ws, size_t ws_size,
                              hipStream_t stream) {
    (void)in_sizes; (void)n_in; (void)out_size; (void)ws_size;
    const float* x  = (const float*)d_in[0];
    const float* tw = (const float*)d_in[1];
    const float* tb = (const float*)d_in[2];
    const float* cw = (const float*)d_in[3];
    const float* cb = (const float*)d_in[4];
    const float* bw = (const float*)d_in[5];
    const float* bb = (const float*)d_in[6];
    const float* ow = (const float*)d_in[7];
    const float* ob = (const float*)d_in[8];
    float* ws  = (float*)d_ws;
    float* out = (float*)d_out;

    _Float16* wbf  = (_Float16*)(ws + WBFO);
    _Float16* wout = wbf + 110592;
    _Float16* xpad = (_Float16*)(ws + XPADO);   // also upad (aliased)
    _Float16* topb = (_Float16*)(ws + TOPO);
    _Float16* cenb = (_Float16*)(ws + CENO);
    _Float16* botb = (_Float16*)(ws + BOTO);

    hipLaunchKernelGGL(k_prep, dim3(1216), dim3(256), 0, stream, bw, ow, tw, cw, wbf, x, xpad);
    hipLaunchKernelGGL(k_convs, dim3(1536), dim3(256), 0, stream, xpad, wbf, tb, cb, bb, topb, cenb, botb);
    hipLaunchKernelGGL(k_attn, dim3(1024), dim3(256), 0, stream, ws);
    hipLaunchKernelGGL(k_finalu, dim3(256), dim3(256), 0, stream, x, ws, xpad);
    hipLaunchKernelGGL(k_conv3o, dim3(1024), dim3(256), 0, stream, xpad, wout, ob, out);
}

// Round 12
// 171.557 us; speedup vs baseline: 1.7675x; 1.0670x over previous
//
#include <hip/hip_runtime.h>
#include <hip/hip_bf16.h>

// Problem constants: B=4, C=64, H=W=64, HW=4096, P=64, Q=3 (CQ=192)
namespace {
constexpr int IMG    = 262144;   // 64*4096 elems per batch image
constexpr int MS     = 4;        // attention m-split
constexpr int PADIMG = 4356;     // 66*66 padded pixels
constexpr float LOG2E = 1.44269504088896340736f;
// workspace float offsets
constexpr int WBFO  = 0;         // fp16 weights: wbot[9][6][64][32], wout[9][6][64][32], wtop[6][64][32], wcen[6][64][32]
constexpr int XPADO = 122880;    // fp16 xp/up padded [b][ck 6][px 4356][32] (aliased: xp then up)
constexpr int TOPO  = 1795584;   // fp16 topT [b][m][p]
constexpr int CENO  = 2319872;   // fp16 cenT [b][n][p]
constexpr int BOTO  = 2844160;   // fp16 bot  [b][c][m]
constexpr int PVO   = 3368448;   // bf16 PV [4][b][n][c]
constexpr int MSO   = 5465600;   // m_s [s 4][b 4][group 256]
constexpr int ZSO   = 5469696;   // z_s
}

using half8v = __attribute__((ext_vector_type(8))) _Float16;
using half4v = __attribute__((ext_vector_type(4))) _Float16;
typedef __attribute__((ext_vector_type(4))) float f32x4;

__device__ __forceinline__ short f2bf(float f) {
    __hip_bfloat16 h = __float2bfloat16(f);
    return *reinterpret_cast<short*>(&h);
}
__device__ __forceinline__ float bf2f(short s) {
    unsigned u = ((unsigned)(unsigned short)s) << 16;
    return __uint_as_float(u);
}

// ---- Dispatch 1: weights->fp16 reorder into k-chunked layouts (blocks 0..959)
// + x-powers into chunked padded xpad incl. border zeroing (blocks 960..1215).
__global__ __launch_bounds__(256) void k_prep(const float* __restrict__ bw, const float* __restrict__ ow,
                                              const float* __restrict__ tw, const float* __restrict__ cw,
                                              _Float16* __restrict__ wbf,
                                              const float* __restrict__ x, _Float16* __restrict__ xpad) {
    __shared__ float xs[64 * 65];
    int bx = blockIdx.x, t = threadIdx.x;
    if (bx < 960) {
        int idx = bx * 256 + t;   // < 245760
        if (idx < 221184) {
            // 3x3: w[o][(p*64+ci)*9+tap] -> wT[tap][ck][o][ki]  (k = ck*32+ki = p*64+ci)
            int tsel = idx / 110592;
            int r    = idx - tsel * 110592;
            int tap  = r / 12288;
            int rr   = r - tap * 12288;
            int ck   = rr / 2048;
            int r2   = rr - ck * 2048;
            int o    = r2 >> 5;
            int ki   = r2 & 31;
            int k    = ck * 32 + ki;
            int p    = k >> 6, ci = k & 63;
            const float* src = tsel ? ow : bw;
            wbf[idx] = (_Float16)src[o * 1728 + (p * 64 + ci) * 9 + tap];
        } else {
            // 1x1: w[o][192] -> wT[ck][o][ki]; center pre-scaled by log2(e)
            int j = idx - 221184;
            int tsel = j / 12288;
            int rr   = j - tsel * 12288;
            int ck   = rr / 2048;
            int r2   = rr - ck * 2048;
            int o    = r2 >> 5;
            int ki   = r2 & 31;
            int k    = ck * 32 + ki;
            wbf[idx] = (_Float16)(tsel ? cw[o * 192 + k] * LOG2E : tw[o * 192 + k]);
        }
        return;
    }
    int bx2 = bx - 960;
    int b = bx2 >> 6, h = bx2 & 63;
    // zero this block's share of the pad border across all 6 chunk planes
    {
        _Float16* base = xpad + (size_t)b * 6 * PADIMG * 32;
        int px[6];
        px[0] = (h + 1) * 66;            // left col, this row
        px[1] = (h + 1) * 66 + 65;       // right col
        px[2] = h;                       // top row px h
        px[3] = 65 * 66 + h;             // bottom row px h
        int npx = 4;
        if (h < 2) { px[4] = 64 + h; px[5] = 65 * 66 + 64 + h; npx = 6; }
        int pi = t / 24, ck = t % 24;    // ck: 6 chunks x 4 quads
        if (pi < npx) {
            int cp = ck >> 2, q = ck & 3;
            half8v z = {0, 0, 0, 0, 0, 0, 0, 0};
            *(half8v*)&base[((size_t)cp * PADIMG + px[pi]) * 32 + q * 8] = z;
        }
    }
    #pragma unroll
    for (int it = 0; it < 16; ++it) {
        int idx = it * 256 + t;
        int ci = idx >> 6, wc = idx & 63;
        xs[ci * 65 + wc] = x[b * IMG + ci * 4096 + h * 64 + wc];
    }
    __syncthreads();
    _Float16* dst = xpad + ((size_t)b * 6 * PADIMG + (h + 1) * 66 + 1) * 32;
    #pragma unroll
    for (int it = 0; it < 6; ++it) {
        int u = it * 256 + t;            // 0..1535: ck plane, px, quad
        int ck = u >> 8, within = u & 255;
        int px = within >> 2, q = within & 3;
        int k0 = ck * 32 + q * 8;
        int p = k0 >> 6, c0 = k0 & 63;   // 8 consecutive k share p (no 64-cross)
        half8v o;
        #pragma unroll
        for (int j = 0; j < 8; ++j) {
            float v = xs[(c0 + j) * 65 + px];
            float pw = (p == 0) ? v : ((p == 1) ? v * v : v * v * v);
            o[j] = (_Float16)pw;
        }
        *(half8v*)&dst[((size_t)ck * PADIMG + px) * 32 + q * 8] = o;
    }
}

// 3x3 SelfONN conv, full-K MFMA implicit GEMM, 32 oc/block, direct output+bias.
// bx in [0,512): oh = bx>>8 (oc half), mt = bx&255 -> (b,h). Coalesced frags.
__device__ __forceinline__ void conv3d32(int bx, int t,
                                         const _Float16* __restrict__ src,
                                         const _Float16* __restrict__ wt,
                                         const float* __restrict__ bias,
                                         _Float16* __restrict__ dh_, float* __restrict__ df) {
    int lane = t & 63, w = t >> 6;
    int l16 = lane & 15, quad = lane >> 4;
    int oh = bx >> 8, mt = bx & 255;
    int b = mt >> 6, h = mt & 63;
    const _Float16* abase = src + ((size_t)b * 6 * PADIMG + (h + 1) * 66 + 1 + w * 16 + l16) * 32 + quad * 8;
    const _Float16* bbase = wt + (size_t)(oh * 32 + l16) * 32 + quad * 8;
    f32x4 acc[2];
    acc[0] = (f32x4){0.f, 0.f, 0.f, 0.f};
    acc[1] = (f32x4){0.f, 0.f, 0.f, 0.f};
    for (int tap = 0; tap < 9; ++tap) {
        int dh = tap / 3 - 1, dw = tap % 3 - 1;
        const _Float16* arow = abase + (dh * 66 + dw) * 32;
        const _Float16* brow = bbase + (size_t)tap * 6 * 2048;
        #pragma unroll
        for (int c6 = 0; c6 < 6; ++c6) {
            half8v afr  = *(const half8v*)&arow[(size_t)c6 * PADIMG * 32];
            half8v bfr0 = *(const half8v*)&brow[(size_t)c6 * 2048];
            half8v bfr1 = *(const half8v*)&brow[(size_t)c6 * 2048 + 512];
            acc[0] = __builtin_amdgcn_mfma_f32_16x16x32_f16(afr, bfr0, acc[0], 0, 0, 0);
            acc[1] = __builtin_amdgcn_mfma_f32_16x16x32_f16(afr, bfr1, acc[1], 0, 0, 0);
        }
    }
    #pragma unroll
    for (int nf = 0; nf < 2; ++nf) {
        int c = oh * 32 + nf * 16 + l16;
        float bv = bias[c];
        size_t oi = (size_t)b * 262144 + (size_t)c * 4096 + h * 64 + w * 16 + quad * 4;
        if (dh_) {
            half4v o;
            #pragma unroll
            for (int r = 0; r < 4; ++r) o[r] = (_Float16)(acc[nf][r] + bv);
            *(half4v*)&dh_[oi] = o;
        } else {
            float4 o = make_float4(acc[nf][0] + bv, acc[nf][1] + bv, acc[nf][2] + bv, acc[nf][3] + bv);
            *(float4*)&df[oi] = o;
        }
    }
}

// ---- Dispatch 2: conv3-bottom (blocks 0..511, direct fp16 out, oc-32) + fused
// top/center 1x1 convs (blocks 512..1023).
__global__ __launch_bounds__(256) void k_convs(const _Float16* __restrict__ xpad,
                                               const _Float16* __restrict__ wbf,
                                               const float* __restrict__ tb, const float* __restrict__ cb,
                                               const float* __restrict__ bbias,
                                               _Float16* __restrict__ topd, _Float16* __restrict__ cend,
                                               _Float16* __restrict__ botb) {
    int bx = blockIdx.x, t = threadIdx.x;
    if (bx < 512) {
        conv3d32(bx, t, xpad, wbf /* wbot at offset 0 */, bbias, botb, nullptr);
        return;
    }
    int bx2 = bx - 512;
    int lane = t & 63, w = t >> 6;
    int l16 = lane & 15, quad = lane >> 4;
    int ot = bx2 >> 8, mt = bx2 & 255;
    int b = mt >> 6, h = mt & 63;
    const _Float16* wt   = wbf + (ot ? 233472 : 221184);   // wcen : wtop
    const float*    bias = ot ? cb : tb;
    _Float16*       dst  = (ot ? cend : topd) + (size_t)b * IMG;
    const _Float16* abase = xpad + ((size_t)b * 6 * PADIMG + (h + 1) * 66 + 1 + w * 16 + l16) * 32 + quad * 8;
    const _Float16* bbase = wt + (size_t)l16 * 32 + quad * 8;
    f32x4 acc[4];
    #pragma unroll
    for (int nf = 0; nf < 4; ++nf) acc[nf] = (f32x4){0.f, 0.f, 0.f, 0.f};
    #pragma unroll
    for (int kc = 0; kc < 6; ++kc) {
        half8v afr = *(const half8v*)&abase[(size_t)kc * PADIMG * 32];
        #pragma unroll
        for (int nf = 0; nf < 4; ++nf) {
            half8v bfr = *(const half8v*)&bbase[(size_t)kc * 2048 + nf * 16 * 32];
            acc[nf] = __builtin_amdgcn_mfma_f32_16x16x32_f16(afr, bfr, acc[nf], 0, 0, 0);
        }
    }
    _Float16* dp = dst + (size_t)(h * 64 + w * 16) * 64;
    #pragma unroll
    for (int nf = 0; nf < 4; ++nf) {
        float bv = bias[nf * 16 + l16];
        if (ot) bv *= LOG2E;   // center output lives in log2e-scaled domain
        #pragma unroll
        for (int r = 0; r < 4; ++r)
            dp[(quad * 4 + r) * 64 + nf * 16 + l16] = (_Float16)(acc[nf][r] + bv);
    }
}

// ---- Dispatch 3: fp16 MFMA flash attention, global softmax, per-wave online max.
// LDS staging + register prefetch pipeline; lp wave-private + XOR swizzle.
// grid 1024: (strip 64) x (b 4) x (split 4).
__global__ __launch_bounds__(256, 4) void k_attn(float* __restrict__ ws) {
    __shared__ _Float16 ltop[64 * 72];   // [m][p]
    __shared__ _Float16 lbot[64 * 72];   // [c][m]
    __shared__ _Float16 lp[64 * 72];     // [n][m swizzled]; wave-private rows
    int t    = threadIdx.x;
    int lane = t & 63, w = t >> 6;
    int l16  = lane & 15, quad = lane >> 4;
    int bx = blockIdx.x;
    int st = bx & 63, b = (bx >> 6) & 3, s = bx >> 8;
    int n0 = st * 64;
    const _Float16* topg = (const _Float16*)(ws + TOPO) + (size_t)b * IMG;
    const _Float16* ceng = (const _Float16*)(ws + CENO) + (size_t)b * IMG;
    const _Float16* botg = (const _Float16*)(ws + BOTO) + (size_t)b * IMG;

    half8v afr[2];
    #pragma unroll
    for (int kk = 0; kk < 2; ++kk)
        afr[kk] = *(const half8v*)&ceng[(size_t)(n0 + w * 16 + l16) * 64 + kk * 32 + quad * 8];

    int r0 = t >> 3, r1 = r0 + 32, off = (t & 7) * 8;
    int q2 = quad >> 1;
    int lpw = (w * 16 + quad * 4) * 72;
    int lpr = (w * 16 + l16) * 72;
    int rb3 = (l16 >> 3) & 1;

    f32x4 pv[4];
    #pragma unroll
    for (int j = 0; j < 4; ++j) pv[j] = (f32x4){0.f, 0.f, 0.f, 0.f};
    float runm = -3.0e38f, zacc = 0.f;

    int mp = s * 1024;
    half8v rt0 = *(const half8v*)&topg[(size_t)(mp + r0) * 64 + off];
    half8v rt1 = *(const half8v*)&topg[(size_t)(mp + r1) * 64 + off];
    half8v rb0 = *(const half8v*)&botg[(size_t)r0 * 4096 + mp + off];
    half8v rb1 = *(const half8v*)&botg[(size_t)r1 * 4096 + mp + off];

    for (int tt = 0; tt < 16; ++tt) {
        __syncthreads();
        *(half8v*)&ltop[r0 * 72 + off] = rt0;
        *(half8v*)&ltop[r1 * 72 + off] = rt1;
        *(half8v*)&lbot[r0 * 72 + off] = rb0;
        *(half8v*)&lbot[r1 * 72 + off] = rb1;
        __syncthreads();
        if (tt < 15) {
            int m1 = s * 1024 + (tt + 1) * 64;
            rt0 = *(const half8v*)&topg[(size_t)(m1 + r0) * 64 + off];
            rt1 = *(const half8v*)&topg[(size_t)(m1 + r1) * 64 + off];
            rb0 = *(const half8v*)&botg[(size_t)r0 * 4096 + m1 + off];
            rb1 = *(const half8v*)&botg[(size_t)r1 * 4096 + m1 + off];
        }
        f32x4 sa[4];
        #pragma unroll
        for (int j = 0; j < 4; ++j) sa[j] = (f32x4){0.f, 0.f, 0.f, 0.f};
        #pragma unroll
        for (int kk = 0; kk < 2; ++kk)
            #pragma unroll
            for (int j = 0; j < 4; ++j) {
                half8v bfr = *(half8v*)&ltop[(j * 16 + l16) * 72 + kk * 32 + quad * 8];
                sa[j] = __builtin_amdgcn_mfma_f32_16x16x32_f16(afr[kk], bfr, sa[j], 0, 0, 0);
            }
        float tm = -3.0e38f;
        #pragma unroll
        for (int j = 0; j < 4; ++j)
            #pragma unroll
            for (int r = 0; r < 4; ++r) tm = fmaxf(tm, sa[j][r]);
        for (int o2 = 32; o2; o2 >>= 1) tm = fmaxf(tm, __shfl_xor(tm, o2, 64));
        float newm = fmaxf(runm, tm);
        if (newm > runm) {
            float sc = exp2f(runm - newm);
            zacc *= sc;
            #pragma unroll
            for (int j = 0; j < 4; ++j) pv[j] *= sc;
            runm = newm;
        }
        #pragma unroll
        for (int j = 0; j < 4; ++j) {
            int cb = (j ^ q2) * 16 + l16;
            #pragma unroll
            for (int r = 0; r < 4; ++r) {
                float e = exp2f(sa[j][r] - runm);
                zacc += e;
                lp[lpw + r * 72 + cb] = (_Float16)e;
            }
        }
        half8v pa[2];
        #pragma unroll
        for (int kk = 0; kk < 2; ++kk) {
            int jj = kk * 2 + q2;
            pa[kk] = *(half8v*)&lp[lpr + ((jj ^ rb3) * 16) + (quad & 1) * 8];
        }
        #pragma unroll
        for (int kk = 0; kk < 2; ++kk)
            #pragma unroll
            for (int j = 0; j < 4; ++j) {
                half8v bb = *(half8v*)&lbot[(j * 16 + l16) * 72 + kk * 32 + quad * 8];
                pv[j] = __builtin_amdgcn_mfma_f32_16x16x32_f16(pa[kk], bb, pv[j], 0, 0, 0);
            }
    }
    for (int o2 = 32; o2; o2 >>= 1) zacc += __shfl_xor(zacc, o2, 64);
    if (lane == 0) {
        ws[MSO + s * 1024 + b * 256 + st * 4 + w] = runm;
        ws[ZSO + s * 1024 + b * 256 + st * 4 + w] = zacc;
    }
    short* pvp = (short*)(ws + PVO) + (size_t)s * 1048576 + (size_t)b * IMG;
    #pragma unroll
    for (int j = 0; j < 4; ++j)
        #pragma unroll
        for (int r = 0; r < 4; ++r)
            pvp[(size_t)(n0 + w * 16 + quad * 4 + r) * 64 + j * 16 + l16] = f2bf(pv[j][r]);
}

// ---- Dispatch 4: inline M/Z reduction + u = x + softmax@bottom + u-powers ->
// chunked padded fp16 (aliases xpad).
__global__ __launch_bounds__(256) void k_finalu(const float* __restrict__ x, float* __restrict__ ws,
                                                _Float16* __restrict__ upad) {
    __shared__ float us[64 * 65];
    __shared__ float rm[4], rz[4];
    int t = threadIdx.x, bx = blockIdx.x;
    int b = bx >> 6, h = bx & 63;
    float mv[4];
    float m = -3.0e38f;
    #pragma unroll
    for (int s = 0; s < 4; ++s) {
        mv[s] = ws[MSO + s * 1024 + b * 256 + t];
        m = fmaxf(m, mv[s]);
    }
    for (int o2 = 32; o2; o2 >>= 1) m = fmaxf(m, __shfl_xor(m, o2, 64));
    if ((t & 63) == 0) rm[t >> 6] = m;
    __syncthreads();
    float M = fmaxf(fmaxf(rm[0], rm[1]), fmaxf(rm[2], rm[3]));
    float z = 0.f;
    #pragma unroll
    for (int s = 0; s < 4; ++s)
        z += ws[ZSO + s * 1024 + b * 256 + t] * exp2f(mv[s] - M);
    for (int o2 = 32; o2; o2 >>= 1) z += __shfl_xor(z, o2, 64);
    if ((t & 63) == 0) rz[t >> 6] = z;
    __syncthreads();
    float Z = rz[0] + rz[1] + rz[2] + rz[3];

    const short* pvb = (const short*)(ws + PVO) + (size_t)b * IMG;
    int hg = h >> 4;
    #pragma unroll
    for (int it = 0; it < 16; ++it) {
        int idx = it * 256 + t;
        int ci = idx >> 6, wc = idx & 63;
        int rem = ci * 4096 + h * 64 + wc;
        int grp = ci * 4 + hg;   // n = ci*64+h; 16-row group = n>>4
        float acc = 0.f;
        #pragma unroll
        for (int s = 0; s < MS; ++s) {
            float scl = exp2f(ws[MSO + s * 1024 + b * 256 + grp] - M);
            acc += bf2f(pvb[(size_t)s * 1048576 + rem]) * scl;
        }
        us[ci * 65 + wc] = x[(size_t)b * IMG + rem] + acc / Z;
    }
    __syncthreads();
    _Float16* dst = upad + ((size_t)b * 6 * PADIMG + (h + 1) * 66 + 1) * 32;
    #pragma unroll
    for (int it = 0; it < 6; ++it) {
        int u = it * 256 + t;
        int ck = u >> 8, within = u & 255;
        int px = within >> 2, q = within & 3;
        int k0 = ck * 32 + q * 8;
        int p = k0 >> 6, c0 = k0 & 63;
        half8v o;
        #pragma unroll
        for (int j = 0; j < 8; ++j) {
            float v = us[(c0 + j) * 65 + px];
            float pw = (p == 0) ? v : ((p == 1) ? v * v : v * v * v);
            o[j] = (_Float16)pw;
        }
        *(half8v*)&dst[((size_t)ck * PADIMG + px) * 32 + q * 8] = o;
    }
}

// ---- Dispatch 5: final 3x3 conv, direct fp32 output + bias, oc-32. grid 512.
__global__ __launch_bounds__(256) void k_conv3o(const _Float16* __restrict__ upad,
                                                const _Float16* __restrict__ wout,
                                                const float* __restrict__ ob,
                                                float* __restrict__ out) {
    conv3d32(blockIdx.x, threadIdx.x, upad, wout, ob, nullptr, out);
}

extern "C" void kernel_launch(void* const* d_in, const int* in_sizes, int n_in,
                              void* d_out, int out_size, void* d_ws, size_t ws_size,
                              hipStream_t stream) {
    (void)in_sizes; (void)n_in; (void)out_size; (void)ws_size;
    const float* x  = (const float*)d_in[0];
    const float* tw = (const float*)d_in[1];
    const float* tb = (const float*)d_in[2];
    const float* cw = (const float*)d_in[3];
    const float* cb = (const float*)d_in[4];
    const float* bw = (const float*)d_in[5];
    const float* bb = (const float*)d_in[6];
    const float* ow = (const float*)d_in[7];
    const float* ob = (const float*)d_in[8];
    float* ws  = (float*)d_ws;
    float* out = (float*)d_out;

    _Float16* wbf  = (_Float16*)(ws + WBFO);
    _Float16* wout = wbf + 110592;
    _Float16* xpad = (_Float16*)(ws + XPADO);   // also upad (aliased)
    _Float16* topb = (_Float16*)(ws + TOPO);
    _Float16* cenb = (_Float16*)(ws + CENO);
    _Float16* botb = (_Float16*)(ws + BOTO);

    hipLaunchKernelGGL(k_prep, dim3(1216), dim3(256), 0, stream, bw, ow, tw, cw, wbf, x, xpad);
    hipLaunchKernelGGL(k_convs, dim3(1024), dim3(256), 0, stream, xpad, wbf, tb, cb, bb, topb, cenb, botb);
    hipLaunchKernelGGL(k_attn, dim3(1024), dim3(256), 0, stream, ws);
    hipLaunchKernelGGL(k_finalu, dim3(256), dim3(256), 0, stream, x, ws, xpad);
    hipLaunchKernelGGL(k_conv3o, dim3(512), dim3(256), 0, stream, xpad, wout, ob, out);
}